// Round 13
// baseline (1622.517 us; speedup 1.0000x reference)
//
#include <hip/hip_runtime.h>
#include <math.h>

#define S_LEN   2048
#define B_SZ    2
#define DM      1024
#define DI      2048
#define NST     64
#define LH      1024
#define NH      16
#define HD      64
#define TT      4096      /* B*S tokens */
#define NEXP    8
#define FF      4096
#define CHK     1024      /* MoE FF chunk */
#define MAXTILE 72
#define INVR2   0.7071067811865476f
#define CHUNK   128       /* scan chunk length */
#define NCH     16        /* S_LEN / CHUNK */

/* ---- workspace layout (offsets in floats) ---- */
#define OFF_POOLED 0
#define OFF_COUNTS 2048
#define OFF_CURSOR 2056
#define OFF_MASKS  2064
#define OFF_NTILE  2072
#define OFF_EOFF   2080
#define OFF_TILEE  2112
#define OFF_TILER  2272
#define OFF_TILEC  2432
#define OFF_TOKE   2592
#define OFF_TOKW   10784
#define OFF_RTOK   18976
#define OFF_RGATE  27168
#define OFF_REXP   35360
#define OFF_ROWOF  43552
#define OFF_LN     65536                       /* 4M f ; hend during scan ; wbc partials */
#define OFF_BIG    (OFF_LN + 4194304)          /* 16M f : phase-multiplexed */
#define OFF_XC     (OFF_BIG + 16777216)        /* 8454144 f */
#define OFF_PPROD  (OFF_XC + 8388608)          /* 65536 f slack of XC */
#define OFF_BC     (OFF_XC + 8454144)          /* 524288 f */
#define OFF_OUT    (OFF_BC + 524288)           /* 4M f */
/* total = 34,209,792 floats = ~130.5 MiB (proven) */

/* MoE-phase BIG sub-offsets (floats) */
#define MB_HB   0
#define MB_W1T  4194304
#define MB_W2T  8388608
#define MB_LNB  12582912

typedef __attribute__((ext_vector_type(8))) short bf8_t;
typedef __attribute__((ext_vector_type(4))) float f4_t;

__device__ inline float b2f(unsigned short u) {
    unsigned v = (unsigned)u << 16; float f; __builtin_memcpy(&f, &v, 4); return f;
}
__device__ inline unsigned short f2b(float f) {
    unsigned u; __builtin_memcpy(&u, &f, 4);
    unsigned r = (u + 0x7fffu + ((u >> 16) & 1u)) >> 16;
    return (unsigned short)r;
}
__device__ inline void split3v(float v, unsigned short& h, unsigned short& m, unsigned short& l) {
    h = f2b(v);
    float t = v - b2f(h);
    m = f2b(t);
    float t2 = t - b2f(m);
    l = f2b(t2);
}
__device__ inline void split3q(float4 v, ushort4& h4, ushort4& m4, ushort4& l4) {
    split3v(v.x, h4.x, m4.x, l4.x);
    split3v(v.y, h4.y, m4.y, l4.y);
    split3v(v.z, h4.z, m4.z, l4.z);
    split3v(v.w, h4.w, m4.w, l4.w);
}
__device__ inline float gelu_tanh(float x) {
    float x3 = x * x * x;
    return 0.5f * x * (1.f + tanhf(0.7978845608028654f * (x + 0.044715f * x3)));
}
__device__ inline void gld16(const void* g, void* l) {
    __builtin_amdgcn_global_load_lds((const __attribute__((address_space(1))) void*)g,
                                     (__attribute__((address_space(3))) void*)l, 16, 0, 0);
}

/* block-wide (256 thr) LayerNorm of one row held as float4/thread */
__device__ inline float4 row_ln(float4 v, const float* __restrict__ g,
                                const float* __restrict__ bta) {
    float s1 = v.x + v.y + v.z + v.w;
    float s2 = v.x * v.x + v.y * v.y + v.z * v.z + v.w * v.w;
#pragma unroll
    for (int off = 32; off; off >>= 1) {
        s1 += __shfl_xor(s1, off);
        s2 += __shfl_xor(s2, off);
    }
    __shared__ float sh1[4], sh2[4];
    int w = threadIdx.x >> 6, lane = threadIdx.x & 63;
    if (lane == 0) { sh1[w] = s1; sh2[w] = s2; }
    __syncthreads();
    float t1 = sh1[0] + sh1[1] + sh1[2] + sh1[3];
    float t2 = sh2[0] + sh2[1] + sh2[2] + sh2[3];
    float mean = t1 * (1.f / 1024.f);
    float var = t2 * (1.f / 1024.f) - mean * mean;
    float rs = rsqrtf(var + 1e-6f);
    float4 gv = ((const float4*)g)[threadIdx.x];
    float4 bv = ((const float4*)bta)[threadIdx.x];
    float4 o;
    o.x = (v.x - mean) * rs * gv.x + bv.x;
    o.y = (v.y - mean) * rs * gv.y + bv.y;
    o.z = (v.z - mean) * rs * gv.z + bv.z;
    o.w = (v.w - mean) * rs * gv.w + bv.w;
    return o;
}

/* ------------ pooled mean over sequence ------------ */
__global__ __launch_bounds__(256) void pooled_k(const float* __restrict__ h0, float* __restrict__ pooled) {
    int d = blockIdx.x * 256 + threadIdx.x;
    int b = blockIdx.y, sc = blockIdx.z;
    float s = 0.f;
    for (int i = 0; i < 128; ++i) {
        int ss = sc * 128 + i;
        s += h0[((size_t)(b * S_LEN + ss)) * DM + d];
    }
    atomicAdd(&pooled[b * DM + d], s * (1.f / 2048.f));
}

/* ------------ router: masks ------------ */
__global__ __launch_bounds__(256) void router_k(const float* __restrict__ pooled,
                                                const float* __restrict__ rw,
                                                const float* __restrict__ rb,
                                                float* __restrict__ masks) {
    int tid = threadIdx.x;
    float p[8] = {0, 0, 0, 0, 0, 0, 0, 0};
    for (int d = tid; d < DM; d += 256) {
        float p0 = pooled[d], p1 = pooled[DM + d];
        float4 w4 = *(const float4*)(rw + (size_t)d * 4);
        p[0] += p0 * w4.x; p[1] += p0 * w4.y; p[2] += p0 * w4.z; p[3] += p0 * w4.w;
        p[4] += p1 * w4.x; p[5] += p1 * w4.y; p[6] += p1 * w4.z; p[7] += p1 * w4.w;
    }
#pragma unroll
    for (int off = 32; off; off >>= 1) {
#pragma unroll
        for (int j = 0; j < 8; ++j) p[j] += __shfl_xor(p[j], off);
    }
    __shared__ float sh[4][8];
    int w = tid >> 6, lane = tid & 63;
    if (lane == 0) {
#pragma unroll
        for (int j = 0; j < 8; ++j) sh[w][j] = p[j];
    }
    __syncthreads();
    if (tid < 8) {
        float v = sh[0][tid] + sh[1][tid] + sh[2][tid] + sh[3][tid] + rb[tid & 3];
        float sc = 1.f / (1.f + expf(-v));
        masks[tid] = (sc > 0.3f) ? 1.f : 0.f;
    }
}

/* ------------ fused: h = hidden (copy) + LN0 -> bf16x3 planes ------------ */
__global__ __launch_bounds__(256) void ln0_copy_k(const float* __restrict__ hid,
                                                  const float* __restrict__ g,
                                                  const float* __restrict__ bta,
                                                  float* __restrict__ hout,
                                                  unsigned short* __restrict__ ph,
                                                  unsigned short* __restrict__ pm,
                                                  unsigned short* __restrict__ pl) {
    int row = blockIdx.x;
    float4 v = ((const float4*)(hid + (size_t)row * DM))[threadIdx.x];
    ((float4*)(hout + (size_t)row * DM))[threadIdx.x] = v;
    float4 o = row_ln(v, g, bta);
    ushort4 h4, m4, l4;
    split3q(o, h4, m4, l4);
    size_t f = (size_t)row * 256 + threadIdx.x;
    ((ushort4*)ph)[f] = h4;
    ((ushort4*)pm)[f] = m4;
    ((ushort4*)pl)[f] = l4;
}

/* ------------ fused: h += mask*src ; LN -> fp32 + bf16x3 planes ------------ */
__global__ __launch_bounds__(256) void add_ln_k(float* __restrict__ h,
                                                const float* __restrict__ src,
                                                const float* __restrict__ masks, int midx,
                                                const float* __restrict__ g,
                                                const float* __restrict__ bta,
                                                float* __restrict__ out,
                                                unsigned short* __restrict__ ph,
                                                unsigned short* __restrict__ pm,
                                                unsigned short* __restrict__ pl) {
    int row = blockIdx.x;
    int b = row >> 11;
    float m = masks[b * 4 + midx];
    float4 hv = ((float4*)(h + (size_t)row * DM))[threadIdx.x];
    float4 sv = ((const float4*)(src + (size_t)row * DM))[threadIdx.x];
    hv.x += m * sv.x; hv.y += m * sv.y; hv.z += m * sv.z; hv.w += m * sv.w;
    ((float4*)(h + (size_t)row * DM))[threadIdx.x] = hv;
    float4 o = row_ln(hv, g, bta);
    ((float4*)(out + (size_t)row * DM))[threadIdx.x] = o;
    ushort4 h4, m4, l4;
    split3q(o, h4, m4, l4);
    size_t f = (size_t)row * 256 + threadIdx.x;
    ((ushort4*)ph)[f] = h4;
    ((ushort4*)pm)[f] = m4;
    ((ushort4*)pl)[f] = l4;
}

/* ------------ fused: timecrystal elementwise ; LN (fp32 out, may alias ln) ------------ */
__global__ __launch_bounds__(256) void tc_ln_k(float* __restrict__ h,
                                               const float* __restrict__ ln,
                                               const float* __restrict__ gm,
                                               const float* __restrict__ tcb,
                                               const float* __restrict__ theta,
                                               const float* __restrict__ masks,
                                               const float* __restrict__ g,
                                               const float* __restrict__ bta,
                                               float* __restrict__ out) {
    int row = blockIdx.x;
    int b = row >> 11;
    float th = theta[0];
    float ct = cosf(th), st = sinf(th);
    float m = masks[b * 4 + 1];
    float4 xv = ((const float4*)(ln + (size_t)row * DM))[threadIdx.x];
    float4 gv = ((const float4*)(gm + (size_t)row * DM))[threadIdx.x];
    float4 bb = ((const float4*)tcb)[threadIdx.x];
    float4 hv = ((float4*)(h + (size_t)row * DM))[threadIdx.x];
    hv.x += m * (ct * xv.x + st * tanhf(gv.x + bb.x));
    hv.y += m * (ct * xv.y + st * tanhf(gv.y + bb.y));
    hv.z += m * (ct * xv.z + st * tanhf(gv.z + bb.z));
    hv.w += m * (ct * xv.w + st * tanhf(gv.w + bb.w));
    ((float4*)(h + (size_t)row * DM))[threadIdx.x] = hv;
    float4 o = row_ln(hv, g, bta);
    ((float4*)(out + (size_t)row * DM))[threadIdx.x] = o;
}

/* ------------ fused: wavelet merge + dwconv + masked add ; LN -> fp32 + bf16 cast ------------ */
__global__ __launch_bounds__(256) void wpost_ln_k(float* __restrict__ h,
                                                  const float* __restrict__ o2,
                                                  const float* __restrict__ det,
                                                  const float* __restrict__ wconv,
                                                  const float* __restrict__ masks,
                                                  const float* __restrict__ g,
                                                  const float* __restrict__ bta,
                                                  float* __restrict__ out,
                                                  unsigned short* __restrict__ outb) {
    int row = blockIdx.x;
    int s = row & 2047;
    int b = row >> 11;
    float m = masks[b * 4 + 2];
    float4 acc = {0.f, 0.f, 0.f, 0.f};
#pragma unroll
    for (int t = 0; t < 4; ++t) {
        int ss = s + t - 2;
        if (ss >= 0 && ss < S_LEN) {
            int l = ss >> 1;
            size_t lr = (size_t)(b * LH + l) * DM;
            float4 ov = ((const float4*)(o2 + lr))[threadIdx.x];
            float4 dv = ((const float4*)(det + lr))[threadIdx.x];
            float sg = (ss & 1) ? -INVR2 : INVR2;
            float4 wv = ((const float4*)(wconv + (size_t)t * DM))[threadIdx.x];
            acc.x = fmaf(wv.x, INVR2 * ov.x + sg * dv.x, acc.x);
            acc.y = fmaf(wv.y, INVR2 * ov.y + sg * dv.y, acc.y);
            acc.z = fmaf(wv.z, INVR2 * ov.z + sg * dv.z, acc.z);
            acc.w = fmaf(wv.w, INVR2 * ov.w + sg * dv.w, acc.w);
        }
    }
    float4 hv = ((float4*)(h + (size_t)row * DM))[threadIdx.x];
    hv.x += m * acc.x; hv.y += m * acc.y; hv.z += m * acc.z; hv.w += m * acc.w;
    ((float4*)(h + (size_t)row * DM))[threadIdx.x] = hv;
    float4 o = row_ln(hv, g, bta);
    ((float4*)(out + (size_t)row * DM))[threadIdx.x] = o;
    ushort4 ob;
    ob.x = f2b(o.x); ob.y = f2b(o.y); ob.z = f2b(o.z); ob.w = f2b(o.w);
    ((ushort4*)(outb))[(size_t)row * 256 + threadIdx.x] = ob;
}

/* ------------ split fp32 -> 3 bf16 planes (same layout) ------------ */
__global__ __launch_bounds__(256) void split3_k(const float* __restrict__ in,
                                                unsigned short* __restrict__ ph,
                                                unsigned short* __restrict__ pm,
                                                unsigned short* __restrict__ pl) {
    size_t f = (size_t)blockIdx.x * 256 + threadIdx.x;
    float4 v = ((const float4*)in)[f];
    ushort4 hh, mm, ll;
    split3q(v, hh, mm, ll);
    ((ushort4*)ph)[f] = hh;
    ((ushort4*)pm)[f] = mm;
    ((ushort4*)pl)[f] = ll;
}

/* ------------ transpose fp32 [K][N] -> 3 bf16 [N][K] planes ------------ */
__global__ __launch_bounds__(256) void transb3_k(const float* __restrict__ in,
                                                 unsigned short* __restrict__ oh,
                                                 unsigned short* __restrict__ om,
                                                 unsigned short* __restrict__ ol,
                                                 int ldi, int ldo) {
    __shared__ float t[64][65];
    const int tid = threadIdx.x;
    const int k0 = blockIdx.x << 6, n0 = blockIdx.y << 6;
    const int rr = tid >> 4, cc = (tid & 15) << 2;
#pragma unroll
    for (int i = 0; i < 4; ++i) {
        float4 v = *(const float4*)(in + (size_t)(k0 + rr + i * 16) * ldi + n0 + cc);
        *(float4*)&t[rr + i * 16][cc] = v;
    }
    __syncthreads();
#pragma unroll
    for (int i = 0; i < 4; ++i) {
        int n = rr + i * 16;
        ushort4 h4, m4, l4;
        split3v(t[cc + 0][n], h4.x, m4.x, l4.x);
        split3v(t[cc + 1][n], h4.y, m4.y, l4.y);
        split3v(t[cc + 2][n], h4.z, m4.z, l4.z);
        split3v(t[cc + 3][n], h4.w, m4.w, l4.w);
        size_t of = (size_t)(n0 + n) * ldo + k0 + cc;
        *(ushort4*)(oh + of) = h4;
        *(ushort4*)(om + of) = m4;
        *(ushort4*)(ol + of) = l4;
    }
}

/* ------------ transb3 multi-source (QKV): z picks src; dst offset z*1048576 elems ------------ */
__global__ __launch_bounds__(256) void transb3m_k(const float* __restrict__ s0,
                                                  const float* __restrict__ s1,
                                                  const float* __restrict__ s2,
                                                  unsigned short* __restrict__ oh,
                                                  unsigned short* __restrict__ om,
                                                  unsigned short* __restrict__ ol) {
    __shared__ float t[64][65];
    const int tid = threadIdx.x;
    const int z = blockIdx.z;
    const float* in = (z == 0) ? s0 : ((z == 1) ? s1 : s2);
    size_t doff = (size_t)z * 1048576;   /* 1024x1024 bf16 elements per source */
    const int k0 = blockIdx.x << 6, n0 = blockIdx.y << 6;
    const int rr = tid >> 4, cc = (tid & 15) << 2;
#pragma unroll
    for (int i = 0; i < 4; ++i) {
        float4 v = *(const float4*)(in + (size_t)(k0 + rr + i * 16) * 1024 + n0 + cc);
        *(float4*)&t[rr + i * 16][cc] = v;
    }
    __syncthreads();
#pragma unroll
    for (int i = 0; i < 4; ++i) {
        int n = rr + i * 16;
        ushort4 h4, m4, l4;
        split3v(t[cc + 0][n], h4.x, m4.x, l4.x);
        split3v(t[cc + 1][n], h4.y, m4.y, l4.y);
        split3v(t[cc + 2][n], h4.z, m4.z, l4.z);
        split3v(t[cc + 3][n], h4.w, m4.w, l4.w);
        size_t of = doff + (size_t)(n0 + n) * 1024 + k0 + cc;
        *(ushort4*)(oh + of) = h4;
        *(ushort4*)(om + of) = m4;
        *(ushort4*)(ol + of) = l4;
    }
}

/* ------------ MoE dual transpose: z<8 -> w1 chunk (ldi 4096), z>=8 -> w2 chunk (ldi 1024) ------------ */
__global__ __launch_bounds__(256) void transb2_k(const float* __restrict__ in1,
                                                 const float* __restrict__ in2,
                                                 unsigned short* __restrict__ out1,
                                                 unsigned short* __restrict__ out2) {
    __shared__ float t[64][65];
    const int tid = threadIdx.x;
    const int z = blockIdx.z;
    const float* in;
    unsigned short* out;
    int ldi;
    if (z < 8) { in = in1 + (size_t)z * 4194304; out = out1 + (size_t)z * 1048576; ldi = 4096; }
    else       { in = in2 + (size_t)(z - 8) * 4194304; out = out2 + (size_t)(z - 8) * 1048576; ldi = 1024; }
    const int k0 = blockIdx.x << 6, n0 = blockIdx.y << 6;
    const int rr = tid >> 4, cc = (tid & 15) << 2;
#pragma unroll
    for (int i = 0; i < 4; ++i) {
        float4 v = *(const float4*)(in + (size_t)(k0 + rr + i * 16) * ldi + n0 + cc);
        *(float4*)&t[rr + i * 16][cc] = v;
    }
    __syncthreads();
#pragma unroll
    for (int i = 0; i < 4; ++i) {
        int n = rr + i * 16;
        ushort4 o;
        o.x = f2b(t[cc + 0][n]); o.y = f2b(t[cc + 1][n]);
        o.z = f2b(t[cc + 2][n]); o.w = f2b(t[cc + 3][n]);
        *(ushort4*)(out + (size_t)(n0 + n) * 1024 + k0 + cc) = o;
    }
}

/* ------------ bf16x3 exact-fp32 MFMA GEMM: C = A @ Bt^T, 128x128 tile, BK=32 ------------ */
__global__ __launch_bounds__(256) void mmx3_k(const unsigned short* __restrict__ Ah,
                                              const unsigned short* __restrict__ Am,
                                              const unsigned short* __restrict__ Al,
                                              const unsigned short* __restrict__ Bh,
                                              const unsigned short* __restrict__ Bm,
                                              const unsigned short* __restrict__ Bl,
                                              float* __restrict__ C,
                                              int lda, int ldb, int ldc, int K) {
    __shared__ unsigned short S[6][4096];   /* 6 planes x [128 rows][32 k], 48 KB */
    const int tid = threadIdx.x;
    const int m0 = (int)blockIdx.x << 7, n0 = (int)blockIdx.y << 7;
    size_t aoff[2], boff[2];
    int dst[2];
#pragma unroll
    for (int c = 0; c < 2; ++c) {
        int idx = tid + (c << 8);
        int r = idx >> 2, sd = idx & 3;
        int ks = (sd ^ (r & 3)) << 3;
        aoff[c] = (size_t)(m0 + r) * lda + ks;
        boff[c] = (size_t)(n0 + r) * ldb + ks;
        dst[c] = idx << 3;
    }
    const int lane = tid & 63;
    const int w = tid >> 6, wr = w >> 1, wc = w & 1;
    const int lrow = lane & 15, lgrp = lane >> 4;
    f4_t acc[4][4];
#pragma unroll
    for (int i = 0; i < 4; ++i)
#pragma unroll
        for (int j = 0; j < 4; ++j) acc[i][j] = (f4_t){0.f, 0.f, 0.f, 0.f};
    int ard[4], brd[4];
#pragma unroll
    for (int t4 = 0; t4 < 4; ++t4) {
        int ra = wr * 64 + t4 * 16 + lrow;
        ard[t4] = ra * 32 + ((lgrp ^ (ra & 3)) << 3);
        int rb = wc * 64 + t4 * 16 + lrow;
        brd[t4] = rb * 32 + ((lgrp ^ (rb & 3)) << 3);
    }
    for (int k0 = 0; k0 < K; k0 += 32) {
        __syncthreads();
#pragma unroll
        for (int c = 0; c < 2; ++c) {
            gld16(Ah + aoff[c] + k0, &S[0][dst[c]]);
            gld16(Am + aoff[c] + k0, &S[1][dst[c]]);
            gld16(Al + aoff[c] + k0, &S[2][dst[c]]);
            gld16(Bh + boff[c] + k0, &S[3][dst[c]]);
            gld16(Bm + boff[c] + k0, &S[4][dst[c]]);
            gld16(Bl + boff[c] + k0, &S[5][dst[c]]);
        }
        __syncthreads();
        bf8_t ah4[4], am4[4], al4[4];
#pragma unroll
        for (int t4 = 0; t4 < 4; ++t4) {
            ah4[t4] = *(const bf8_t*)&S[0][ard[t4]];
            am4[t4] = *(const bf8_t*)&S[1][ard[t4]];
            al4[t4] = *(const bf8_t*)&S[2][ard[t4]];
        }
#pragma unroll
        for (int ni = 0; ni < 4; ++ni) {
            bf8_t bh = *(const bf8_t*)&S[3][brd[ni]];
            bf8_t bm = *(const bf8_t*)&S[4][brd[ni]];
            bf8_t bl = *(const bf8_t*)&S[5][brd[ni]];
#pragma unroll
            for (int mi = 0; mi < 4; ++mi) {
                acc[mi][ni] = __builtin_amdgcn_mfma_f32_16x16x32_bf16(ah4[mi], bh, acc[mi][ni], 0, 0, 0);
                acc[mi][ni] = __builtin_amdgcn_mfma_f32_16x16x32_bf16(am4[mi], bh, acc[mi][ni], 0, 0, 0);
                acc[mi][ni] = __builtin_amdgcn_mfma_f32_16x16x32_bf16(al4[mi], bh, acc[mi][ni], 0, 0, 0);
                acc[mi][ni] = __builtin_amdgcn_mfma_f32_16x16x32_bf16(ah4[mi], bm, acc[mi][ni], 0, 0, 0);
                acc[mi][ni] = __builtin_amdgcn_mfma_f32_16x16x32_bf16(am4[mi], bm, acc[mi][ni], 0, 0, 0);
                acc[mi][ni] = __builtin_amdgcn_mfma_f32_16x16x32_bf16(ah4[mi], bl, acc[mi][ni], 0, 0, 0);
            }
        }
    }
#pragma unroll
    for (int mi = 0; mi < 4; ++mi) {
#pragma unroll
        for (int j = 0; j < 4; ++j) {
            int rr = wr * 64 + mi * 16 + lgrp * 4 + j;
#pragma unroll
            for (int ni = 0; ni < 4; ++ni) {
                int col = n0 + wc * 64 + ni * 16 + lrow;
                C[(size_t)(m0 + rr) * ldc + col] = acc[mi][ni][j];
            }
        }
    }
}

/* ------------ MFMA GEMM (MoE experts): MODE 2 gemm1, 3 gemm2 accum, 4 gemm2 init+bias2 ------------ */
template<int MODE>
__global__ __launch_bounds__(256) void mm_k(const unsigned short* __restrict__ A,
                                            const unsigned short* __restrict__ Bt,
                                            void* __restrict__ Cv,
                                            int lda, int ldb, int ldc, int K,
                                            const float* __restrict__ bias, int fofs,
                                            const int* __restrict__ ntile,
                                            const int* __restrict__ tileE,
                                            const int* __restrict__ tileR,
                                            const int* __restrict__ tileC,
                                            const int* __restrict__ rtok) {
    __shared__ unsigned short As[8192];
    __shared__ unsigned short Bs[8192];
    const int tid = threadIdx.x;
    int m0 = 0;
    const int n0 = (int)blockIdx.y << 7;
    int cnt = 128, e = 0, row0 = 0;
    if constexpr (MODE >= 2) {
        if ((int)blockIdx.x >= ntile[0]) return;
        e = tileE[blockIdx.x]; row0 = tileR[blockIdx.x]; cnt = tileC[blockIdx.x];
    } else {
        m0 = (int)blockIdx.x << 7;
    }
    const unsigned short* Bp = Bt;
    if constexpr (MODE >= 2) Bp += (size_t)e << 20;
    size_t aoff[4], boff[4];
#pragma unroll
    for (int c = 0; c < 4; ++c) {
        int r = (tid >> 3) + 32 * c;
        int ks = ((tid & 7) ^ (r & 7)) << 3;
        int gr;
        if constexpr (MODE == 2)      gr = rtok[row0 + (r < cnt ? r : cnt - 1)];
        else if constexpr (MODE >= 3) gr = row0 + (r < cnt ? r : cnt - 1);
        else                          gr = m0 + r;
        aoff[c] = (size_t)gr * lda + ks;
        boff[c] = (size_t)(n0 + r) * ldb + ks;
    }
    const int lane = tid & 63;
    const int w = tid >> 6, wr = w >> 1, wc = w & 1;
    const int lrow = lane & 15, lgrp = lane >> 4;
    f4_t acc[4][4];
#pragma unroll
    for (int i = 0; i < 4; ++i)
#pragma unroll
        for (int j = 0; j < 4; ++j) acc[i][j] = (f4_t){0.f, 0.f, 0.f, 0.f};
    int ard[4][2], brd[4][2];
#pragma unroll
    for (int t4 = 0; t4 < 4; ++t4)
#pragma unroll
        for (int kk = 0; kk < 2; ++kk) {
            int ra = wr * 64 + t4 * 16 + lrow;
            ard[t4][kk] = ra * 64 + (((lgrp + (kk << 2)) ^ (ra & 7)) << 3);
            int rb = wc * 64 + t4 * 16 + lrow;
            brd[t4][kk] = rb * 64 + (((lgrp + (kk << 2)) ^ (rb & 7)) << 3);
        }
    for (int k0 = 0; k0 < K; k0 += 64) {
        __syncthreads();
#pragma unroll
        for (int c = 0; c < 4; ++c)
            gld16(A + aoff[c] + k0, As + c * 2048 + tid * 8);
#pragma unroll
        for (int c = 0; c < 4; ++c)
            gld16(Bp + boff[c] + k0, Bs + c * 2048 + tid * 8);
        __syncthreads();
        bf8_t af[4][2], bfv[4][2];
#pragma unroll
        for (int t4 = 0; t4 < 4; ++t4) {
            af[t4][0]  = *(const bf8_t*)&As[ard[t4][0]];
            af[t4][1]  = *(const bf8_t*)&As[ard[t4][1]];
            bfv[t4][0] = *(const bf8_t*)&Bs[brd[t4][0]];
            bfv[t4][1] = *(const bf8_t*)&Bs[brd[t4][1]];
        }
#pragma unroll
        for (int mi = 0; mi < 4; ++mi)
#pragma unroll
            for (int ni = 0; ni < 4; ++ni) {
                acc[mi][ni] = __builtin_amdgcn_mfma_f32_16x16x32_bf16(af[mi][0], bfv[ni][0], acc[mi][ni], 0, 0, 0);
                acc[mi][ni] = __builtin_amdgcn_mfma_f32_16x16x32_bf16(af[mi][1], bfv[ni][1], acc[mi][ni], 0, 0, 0);
            }
    }
#pragma unroll
    for (int mi = 0; mi < 4; ++mi) {
#pragma unroll
        for (int j = 0; j < 4; ++j) {
            int lr = wr * 64 + mi * 16 + lgrp * 4 + j;
            if constexpr (MODE >= 2) { if (lr >= cnt) continue; }
#pragma unroll
            for (int ni = 0; ni < 4; ++ni) {
                int col = n0 + wc * 64 + ni * 16 + lrow;
                float vv = acc[mi][ni][j];
                if constexpr (MODE == 0) {
                    ((float*)Cv)[(size_t)(m0 + lr) * ldc + col] = vv;
                } else if constexpr (MODE == 1) {
                    ((unsigned short*)Cv)[(size_t)(m0 + lr) * ldc + col] = f2b(vv);
                } else if constexpr (MODE == 2) {
                    float bz = bias[(size_t)e * FF + fofs + col];
                    ((unsigned short*)Cv)[(size_t)(row0 + lr) * ldc + col] = f2b(gelu_tanh(vv + bz));
                } else if constexpr (MODE == 3) {
                    ((float*)Cv)[(size_t)(row0 + lr) * ldc + col] += vv;
                } else { /* MODE 4: init with expert output bias b2 */
                    ((float*)Cv)[(size_t)(row0 + lr) * ldc + col] = vv + bias[(size_t)e * DM + col];
                }
            }
        }
    }
}

/* ------------ split-K fp32 GEMM for wbc ------------ */
__global__ __launch_bounds__(256) void gemmsk_f32(const float* __restrict__ A, int lda,
                                                  const float* __restrict__ B, int ldb,
                                                  float* __restrict__ P, int ldc, int Kslab) {
    __shared__ float As[16][68];
    __shared__ float Bs[16][68];
    const int tid = threadIdx.x;
    const int tx = tid & 15, ty = tid >> 4;
    const int m0 = blockIdx.x * 64, n0 = blockIdx.y * 64;
    const int kbeg = blockIdx.z * Kslab, kend = kbeg + Kslab;
    P += (size_t)blockIdx.z * 4096 * 128;
    const int la_r = tid >> 2, la_k = (tid & 3) << 2;
    const int lb_r = tid >> 4, lb_n = (tid & 15) << 2;
    float acc[4][4] = {};
    for (int k0 = kbeg; k0 < kend; k0 += 16) {
        float4 av = *(const float4*)(A + (size_t)(m0 + la_r) * lda + k0 + la_k);
        float4 bv = *(const float4*)(B + (size_t)(k0 + lb_r) * ldb + n0 + lb_n);
        __syncthreads();
        As[la_k + 0][la_r] = av.x; As[la_k + 1][la_r] = av.y;
        As[la_k + 2][la_r] = av.z; As[la_k + 3][la_r] = av.w;
        *(float4*)&Bs[lb_r][lb_n] = bv;
        __syncthreads();
#pragma unroll
        for (int kk = 0; kk < 16; ++kk) {
            float4 a4 = *(const float4*)&As[kk][ty << 2];
            float4 b4 = *(const float4*)&Bs[kk][tx << 2];
            float aa[4] = {a4.x, a4.y, a4.z, a4.w};
            float bb[4] = {b4.x, b4.y, b4.z, b4.w};
#pragma unroll
            for (int i = 0; i < 4; ++i)
#pragma unroll
                for (int j = 0; j < 4; ++j)
                    acc[i][j] = fmaf(aa[i], bb[j], acc[i][j]);
        }
    }
#pragma unroll
    for (int i = 0; i < 4; ++i) {
        int m = m0 + (ty << 2) + i;
        float4 o;
        o.x = acc[i][0]; o.y = acc[i][1]; o.z = acc[i][2]; o.w = acc[i][3];
        *(float4*)(P + (size_t)m * ldc + n0 + (tx << 2)) = o;
    }
}

/* ------------ reduce 8 wbc partials (deterministic order) ------------ */
__global__ __launch_bounds__(256) void wbc_red_k(const float* __restrict__ part,
                                                 float* __restrict__ bc) {
    size_t i = (size_t)blockIdx.x * 256 + threadIdx.x;
    float s = 0.f;
#pragma unroll
    for (int z = 0; z < 8; ++z) s += part[(size_t)z * 524288 + i];
    bc[i] = s;
}

/* ------------ mamba causal dwconv + silu (4 s-positions per thread) ------------ */
__global__ __launch_bounds__(256) void mamba_conv_k(const float* __restrict__ xz,
                                                    const float* __restrict__ cw,
                                                    float* __restrict__ xc) {
    size_t i = (size_t)blockIdx.x * 256 + threadIdx.x;   /* over TT*DI/4 = 2M */
    int c = (int)(i & (DI - 1));
    size_t g = i >> 11;
    int sg = (int)(g & 511);
    int b = (int)(g >> 9);
    int s0 = sg << 2;
    const float* base = xz + ((size_t)b * S_LEN) * 4096 + c;
    float x[7];
#pragma unroll
    for (int t = 0; t < 7; ++t) {
        int ss = s0 - 3 + t;
        x[t] = (ss >= 0) ? base[(size_t)ss * 4096] : 0.f;
    }
    float w0 = cw[0 * DI + c], w1 = cw[1 * DI + c];
    float w2 = cw[2 * DI + c], w3 = cw[3 * DI + c];
    float* out = xc + ((size_t)(b * S_LEN + s0)) * DI + c;
#pragma unroll
    for (int j = 0; j < 4; ++j) {
        float acc = 0.f;
        acc = fmaf(w0, x[j + 0], acc);
        acc = fmaf(w1, x[j + 1], acc);
        acc = fmaf(w2, x[j + 2], acc);
        acc = fmaf(w3, x[j + 3], acc);
        float sg2 = 1.f / (1.f + expf(-acc));
        out[(size_t)j * DI] = acc * sg2;
    }
}

/* ------------ mamba chunked scan, pass 1 ------------ */
__global__ __launch_bounds__(256) void scan1_k(const float* __restrict__ xc,
                                               const float* __restrict__ bc,
                                               const float* __restrict__ alog,
                                               const float* __restrict__ wdt,
                                               const float* __restrict__ dtb,
                                               float* __restrict__ hend,
                                               float* __restrict__ pprod) {
    const int b = blockIdx.z, k = blockIdx.y;
    const int c = blockIdx.x * 256 + threadIdx.x;
    __shared__ float Bs[CHUNK][64];
    const int s0 = k * CHUNK;
    const float4* bc4 = (const float4*)(bc + ((size_t)(b * S_LEN + s0)) * 128);
    for (int idx = threadIdx.x; idx < CHUNK * 16; idx += 256) {
        int r = idx >> 4, q = idx & 15;
        *(float4*)&Bs[r][q << 2] = bc4[r * 32 + q];
    }
    __syncthreads();
    const float A = -expf(alog[c]);
    const float wdtc = wdt[c], dtbc = dtb[c];
    float hs[NST];
#pragma unroll
    for (int n = 0; n < NST; ++n) hs[n] = 0.f;
    float dtsum = 0.f;
    const float* xcp = xc + ((size_t)(b * S_LEN + s0)) * DI + c;
    for (int s = 0; s < CHUNK; ++s) {
        float xcv = xcp[(size_t)s * DI];
        float t = fmaf(xcv, wdtc, dtbc);
        float dtv = (t > 20.f) ? t : log1pf(expf(t));
        float decay = expf(dtv * A);
        float coef = dtv * xcv;
        dtsum += dtv;
#pragma unroll
        for (int n4 = 0; n4 < 16; ++n4) {
            float4 bv = *(const float4*)&Bs[s][n4 << 2];
            hs[n4 * 4 + 0] = fmaf(decay, hs[n4 * 4 + 0], coef * bv.x);
            hs[n4 * 4 + 1] = fmaf(decay, hs[n4 * 4 + 1], coef * bv.y);
            hs[n4 * 4 + 2] = fmaf(decay, hs[n4 * 4 + 2], coef * bv.z);
            hs[n4 * 4 + 3] = fmaf(decay, hs[n4 * 4 + 3], coef * bv.w);
        }
    }
    float* hp = hend + (((size_t)(b * NCH + k)) * DI + c) * NST;
#pragma unroll
    for (int n = 0; n < NST; n += 4) {
        float4 v; v.x = hs[n]; v.y = hs[n + 1]; v.z = hs[n + 2]; v.w = hs[n + 3];
        *(float4*)(hp + n) = v;
    }
    pprod[((size_t)(b * NCH + k)) * DI + c] = expf(dtsum * A);
}

/* ------------ scan pass 2 ------------ */
__global__ __launch_bounds__(256) void scan2_k(const float* __restrict__ hend,
                                               const float* __restrict__ pprod,
                                               float* __restrict__ hin) {
    size_t g = (size_t)blockIdx.x * 256 + threadIdx.x;
    int n = (int)(g & 63);
    int c = (int)((g >> 6) & (DI - 1));
    int b = (int)(g >> 17);
    float h = 0.f;
    for (int k = 0; k < NCH; ++k) {
        size_t base = (size_t)(b * NCH + k) * DI + c;
        hin[base * NST + n] = h;
        h = fmaf(pprod[base], h, hend[base * NST + n]);
    }
}

/* ------------ scan pass 3 ------------ */
__global__ __launch_bounds__(256) void scan3_k(float* __restrict__ xcio,
                                               const float* __restrict__ bc,
                                               const float* __restrict__ xz,
                                               const float* __restrict__ alog,
                                               const float* __restrict__ wdt,
                                               const float* __restrict__ dtb,
                                               const float* __restrict__ dskip,
                                               const float* __restrict__ hin) {
    const int b = blockIdx.z, k = blockIdx.y;
    const int c = blockIdx.x * 256 + threadIdx.x;
    __shared__ float Bs[CHUNK][64];
    __shared__ float Cs[CHUNK][64];
    const int s0 = k * CHUNK;
    const float4* bc4 = (const float4*)(bc + ((size_t)(b * S_LEN + s0)) * 128);
    for (int idx = threadIdx.x; idx < CHUNK * 32; idx += 256) {
        int r = idx >> 5, q = idx & 31;
        float4 v = bc4[r * 32 + q];
        if (q < 16) *(float4*)&Bs[r][q << 2] = v;
        else        *(float4*)&Cs[r][(q - 16) << 2] = v;
    }
    __syncthreads();
    const float A = -expf(alog[c]);
    const float wdtc = wdt[c], dtbc = dtb[c], skipc = dskip[c];
    float hs[NST];
    const float* hp = hin + (((size_t)(b * NCH + k)) * DI + c) * NST;
#pragma unroll
    for (int n = 0; n < NST; n += 4) {
        float4 v = *(const float4*)(hp + n);
        hs[n] = v.x; hs[n + 1] = v.y; hs[n + 2] = v.z; hs[n + 3] = v.w;
    }
    float* xcp = xcio + ((size_t)(b * S_LEN + s0)) * DI + c;
    const float* zp = xz + ((size_t)(b * S_LEN + s0)) * 4096 + DI + c;
    for (int s = 0; s < CHUNK; ++s) {
        float xcv = xcp[(size_t)s * DI];
        float t = fmaf(xcv, wdtc, dtbc);
        float dtv = (t > 20.f) ? t : log1pf(expf(t));
        float decay = expf(dtv * A);
        float coef = dtv * xcv;
        float y = 0.f;
#pragma unroll
        for (int n4 = 0; n4 < 16; ++n4) {
            float4 bv = *(const float4*)&Bs[s][n4 << 2];
            float4 cv = *(const float4*)&Cs[s][n4 << 2];
            float h0 = fmaf(decay, hs[n4 * 4 + 0], coef * bv.x);
            float h1 = fmaf(decay, hs[n4 * 4 + 1], coef * bv.y);
            float h2 = fmaf(decay, hs[n4 * 4 + 2], coef * bv.z);
            float h3 = fmaf(decay, hs[n4 * 4 + 3], coef * bv.w);
            hs[n4 * 4 + 0] = h0; hs[n4 * 4 + 1] = h1;
            hs[n4 * 4 + 2] = h2; hs[n4 * 4 + 3] = h3;
            y = fmaf(h0, cv.x, y); y = fmaf(h1, cv.y, y);
            y = fmaf(h2, cv.z, y); y = fmaf(h3, cv.w, y);
        }
        y = fmaf(skipc, xcv, y);
        float z = zp[(size_t)s * 4096];
        float sz = z / (1.f + expf(-z));
        xcp[(size_t)s * DI] = y * sz;
    }
}

/* ------------ wavelet split -> a bf16x3 planes + det fp32 ------------ */
__global__ __launch_bounds__(256) void wsplit_k(const float* __restrict__ ln,
                                                unsigned short* __restrict__ ah,
                                                unsigned short* __restrict__ am,
                                                unsigned short* __restrict__ al,
                                                float* __restrict__ det) {
    size_t f = (size_t)blockIdx.x * 256 + threadIdx.x;
    int d4 = (int)(f & 255);
    size_t l = f >> 8;
    size_t b = l >> 10;
    size_t li = l & 1023;
    const float4* ln4 = (const float4*)ln;
    float4 xe = ln4[(b * S_LEN + 2 * li) * 256 + d4];
    float4 xo = ln4[(b * S_LEN + 2 * li + 1) * 256 + d4];
    float4 av, dv;
    av.x = (xe.x + xo.x) * INVR2; dv.x = (xe.x - xo.x) * INVR2;
    av.y = (xe.y + xo.y) * INVR2; dv.y = (xe.y - xo.y) * INVR2;
    av.z = (xe.z + xo.z) * INVR2; dv.z = (xe.z - xo.z) * INVR2;
    av.w = (xe.w + xo.w) * INVR2; dv.w = (xe.w - xo.w) * INVR2;
    ushort4 h4, m4, l4;
    split3q(av, h4, m4, l4);
    ((ushort4*)ah)[f] = h4;
    ((ushort4*)am)[f] = m4;
    ((ushort4*)al)[f] = l4;
    ((float4*)det)[f] = dv;
}

/* ------------ attention partial: half KV, fused-qkv input (stride 3072),
   R8 3-buffer structure + K/V register prefetch (loads overlap compute) ------------ */
__global__ __launch_bounds__(256) void wlam_attn_k(const float* __restrict__ qkv,
                                                   float* __restrict__ o0,
                                                   float* __restrict__ o1,
                                                   float* __restrict__ ml) {
    __shared__ float Qt[64][68];
    __shared__ float KPt[64][68];
    __shared__ float Vs[64][68];
    const int tid = threadIdx.x;
    const int b = blockIdx.z >> 1, half = blockIdx.z & 1;
    const int hh = blockIdx.y;
    const int q0 = blockIdx.x << 6;
    const int tx = tid & 15, ty = tid >> 4;
    const int sr = tid & 63, sc4 = (tid >> 6) << 4;
    {
        const float* qp = qkv + ((size_t)(b * LH + q0 + sr)) * 3072 + hh * HD + sc4;
        float4 v0 = *(const float4*)qp;
        float4 v1 = *(const float4*)(qp + 4);
        float4 v2 = *(const float4*)(qp + 8);
        float4 v3 = *(const float4*)(qp + 12);
        Qt[sc4 + 0][sr] = v0.x;  Qt[sc4 + 1][sr] = v0.y;  Qt[sc4 + 2][sr] = v0.z;  Qt[sc4 + 3][sr] = v0.w;
        Qt[sc4 + 4][sr] = v1.x;  Qt[sc4 + 5][sr] = v1.y;  Qt[sc4 + 6][sr] = v1.z;  Qt[sc4 + 7][sr] = v1.w;
        Qt[sc4 + 8][sr] = v2.x;  Qt[sc4 + 9][sr] = v2.y;  Qt[sc4 + 10][sr] = v2.z; Qt[sc4 + 11][sr] = v2.w;
        Qt[sc4 + 12][sr] = v3.x; Qt[sc4 + 13][sr] = v3.y; Qt[sc4 + 14][sr] = v3.z; Qt[sc4 + 15][sr] = v3.w;
    }
    float mrow[4] = {-INFINITY, -INFINITY, -INFINITY, -INFINITY};
    float lrow[4] = {0.f, 0.f, 0.f, 0.f};
    float oacc[4][4] = {};
    const int c0beg = half << 9;
    float4 kr0, kr1, kr2, kr3, vr0, vr1, vr2, vr3;
#define LDKV(C0SRC) { \
        const float* kp_ = qkv + ((size_t)(b * LH + (C0SRC) + sr)) * 3072 + 1024 + hh * HD + sc4; \
        kr0 = *(const float4*)kp_;        kr1 = *(const float4*)(kp_ + 4); \
        kr2 = *(const float4*)(kp_ + 8);  kr3 = *(const float4*)(kp_ + 12); \
        const float* vp_ = kp_ + 1024; \
        vr0 = *(const float4*)vp_;        vr1 = *(const float4*)(vp_ + 4); \
        vr2 = *(const float4*)(vp_ + 8);  vr3 = *(const float4*)(vp_ + 12); }
    LDKV(c0beg);
    for (int c0 = c0beg; c0 < c0beg + 512; c0 += 64) {
        __syncthreads();   /* previous tile's PV reads done */
        {
            KPt[sc4 + 0][sr] = kr0.x;  KPt[sc4 + 1][sr] = kr0.y;  KPt[sc4 + 2][sr] = kr0.z;  KPt[sc4 + 3][sr] = kr0.w;
            KPt[sc4 + 4][sr] = kr1.x;  KPt[sc4 + 5][sr] = kr1.y;  KPt[sc4 + 6][sr] = kr1.z;  KPt[sc4 + 7][sr] = kr1.w;
            KPt[sc4 + 8][sr] = kr2.x;  KPt[sc4 + 9][sr] = kr2.y;  KPt[sc4 + 10][sr] = kr2.z; KPt[sc4 + 11][sr] = kr2.w;
            KPt[sc4 + 12][sr] = kr3.x; KPt[sc4 + 13][sr] = kr3.y; KPt[sc4 + 14][sr] = kr3.z; KPt[sc4 + 15][sr] = kr3.w;
            *(float4*)&Vs[sr][sc4 + 0]  = vr0;
            *(float4*)&Vs[sr][sc4 + 4]  = vr1;
            *(float4*)&Vs[sr][sc4 + 8]  = vr2;
            *(float4*)&Vs[sr][sc4 + 12] = vr3;
        }
        __syncthreads();   /* staging visible */
        if (c0 + 64 < c0beg + 512) LDKV(c0 + 64);   /* prefetch next tile; latency hides under compute */
        float s[4][4] = {};
#pragma unroll
        for (int d = 0; d < 64; ++d) {
            float4 a4 = *(const float4*)&Qt[d][ty << 2];
            float4 b4 = *(const float4*)&KPt[d][tx << 2];
            float aa[4] = {a4.x, a4.y, a4.z, a4.w};
            float bb[4] = {b4.x, b4.y, b4.z, b4.w};
#pragma unroll
            for (int i = 0; i < 4; ++i)
#pragma unroll
                for (int j = 0; j < 4; ++j)
                    s[i][j] = fmaf(aa[i], bb[j], s[i][j]);
        }
        float rm[4], mn[4], corr[4], rs[4];
#pragma unroll
        for (int i = 0; i < 4; ++i) {
            s[i][0] *= 0.125f; s[i][1] *= 0.125f; s[i][2] *= 0.125f; s[i][3] *= 0.125f;
            rm[i] = fmaxf(fmaxf(s[i][0], s[i][1]), fmaxf(s[i][2], s[i][3]));
        }
#pragma unroll
        for (int off = 8; off; off >>= 1) {
#pragma unroll
            for (int i = 0; i < 4; ++i) rm[i] = fmaxf(rm[i], __shfl_xor(rm[i], off));
        }
#pragma unroll
        for (int i = 0; i < 4; ++i) {
            mn[i] = fmaxf(mrow[i], rm[i]);
            corr[i] = expf(mrow[i] - mn[i]);
            mrow[i] = mn[i];
            s[i][0] = expf(s[i][0] - mn[i]); s[i][1] = expf(s[i][1] - mn[i]);
            s[i][2] = expf(s[i][2] - mn[i]); s[i][3] = expf(s[i][3] - mn[i]);
            rs[i] = (s[i][0] + s[i][1]) + (s[i][2] + s[i][3]);
        }
#pragma unroll
        for (int off = 8; off; off >>= 1) {
#pragma unroll
            for (int i = 0; i < 4; ++i) rs[i] += __shfl_xor(rs[i], off);
        }
#pragma unroll
        for (int i = 0; i < 4; ++i) {
            lrow[i] = lrow[i] * corr[i] + rs[i];
            oacc[i][0] *= corr[i]; oacc[i][1] *= corr[i];
            oacc[i][2] *= corr[i]; oacc[i][3] *= corr[i];
        }
        __syncthreads();   /* all QK reads of KPt done */
#pragma unroll
        for (int j = 0; j < 4; ++j) {
            float4 pv; pv.x = s[0][j]; pv.y = s[1][j]; pv.z = s[2][j]; pv.w = s[3][j];
            *(float4*)&KPt[(tx << 2) + j][ty << 2] = pv;
        }
        __syncthreads();
#pragma unroll
        for (int kk = 0; kk < 64; ++kk) {
            float4 pa = *(const float4*)&KPt[kk][ty << 2];
            float4 vb = *(const float4*)&Vs[kk][tx << 2];
            float aa[4] = {pa.x, pa.y, pa.z, pa.w};
            float bb[4] = {vb.x, vb.y, vb.z, vb.w};
#pragma unroll
            for (int i = 0; i < 4; ++i)
#pragma unroll
                for (int j = 0; j < 4; ++j)
                    oacc[i][j] = fmaf(aa[i], bb[j], oacc[i][j]);
        }
    }
#undef LDKV
    float* op = half ? o1 : o0;
#pragma unroll
    for (int i = 0; i < 4; ++i) {
        int rrow = q0 + (ty << 2) + i;
        float4 ov;
        ov.x = oacc[i][0]; ov.y = oacc[i][1]; ov.z = oacc[i][2]; ov.w = oacc[i][3];
        *(float4*)(op + ((size_t)(b * LH + rrow)) * DM + hh * HD + (tx << 2)) = ov;
        if (tx == 0) {
            size_t mi = (size_t)half * 65536 + ((size_t)(b * LH + rrow) * NH + hh) * 2;
            ml[mi] = mrow[i];
            ml[mi + 1] = lrow[i];
        }
    }
}

/* ------------ attention merge: exact 2-way softmax merge -> bf16x3 planes ------------ */
__global__ __launch_bounds__(256) void attn_merge_k(const float* __restrict__ o0,
                                                    const float* __restrict__ o1,
                                                    const float* __restrict__ ml,
                                                    unsigned short* __restrict__ ph,
                                                    unsigned short* __restrict__ pm,
                                                    unsigned short* __restrict__ pl) {
    int row = blockIdx.x;
    int t = threadIdx.x;
    int hh = t >> 4;
    size_t idx = ((size_t)row * NH + hh) * 2;
    float m0 = ml[idx], l0 = ml[idx + 1];
    float m1 = ml[65536 + idx], l1 = ml[65536 + idx + 1];
    float m = fmaxf(m0, m1);
    float w0 = expf(m0 - m), w1 = expf(m1 - m);
    float inv = 1.f / (l0 * w0 + l1 * w1);
    float4 a = ((const float4*)(o0 + (size_t)row * DM))[t];
    float4 bv = ((const float4*)(o1 + (size_t)row * DM))[t];
    float4 o;
    o.x = (a.x * w0 + bv.x * w1) * inv;
    o.y = (a.y * w0 + bv.y * w1) * inv;
    o.z = (a.z * w0 + bv.z * w1) * inv;
    o.w = (a.w * w0 + bv.w * w1) * inv;
    ushort4 h4, m4, l4;
    split3q(o, h4, m4, l4);
    size_t f = (size_t)row * 256 + t;
    ((ushort4*)ph)[f] = h4;
    ((ushort4*)pm)[f] = m4;
    ((ushort4*)pl)[f] = l4;
}

/* ------------ MoE gate (fp32): top-2 + softmax ------------ */
__global__ __launch_bounds__(256) void moe_gate_k(const float* __restrict__ X,
                                                  const float* __restrict__ wg,
                                                  int* __restrict__ toke,
                                                  float* __restrict__ tokw) {
    const int wv = threadIdx.x >> 6, lane = threadIdx.x & 63;
    const int t = blockIdx.x * 4 + wv;
    const float* x = X + (size_t)t * DM;
    float acc[8] = {0, 0, 0, 0, 0, 0, 0, 0};
    for (int d = lane; d < DM; d += 64) {
        float xv = x[d];
        const float4* wg4 = (const float4*)(wg + (size_t)d * 8);
        float4 wa = wg4[0], wb = wg4[1];
        acc[0] = fmaf(xv, wa.x, acc[0]); acc[1] = fmaf(xv, wa.y, acc[1]);
        acc[2] = fmaf(xv, wa.z, acc[2]); acc[3] = fmaf(xv, wa.w, acc[3]);
        acc[4] = fmaf(xv, wb.x, acc[4]); acc[5] = fmaf(xv, wb.y, acc[5]);
        acc[6] = fmaf(xv, wb.z, acc[6]); acc[7] = fmaf(xv, wb.w, acc[7]);
    }
#pragma unroll
    for (int off = 32; off; off >>= 1) {
#pragma unroll
        for (int j = 0; j < 8; ++j) acc[j] += __shfl_xor(acc[j], off);
    }
    if (lane == 0) {
        int i0 = 0; float v0 = acc[0];
#pragma unroll
        for (int e2 = 1; e2 < 8; ++e2) if (acc[e2] > v0) { v0 = acc[e2]; i0 = e2; }
        int i1 = -1; float v1 = -INFINITY;
#pragma unroll
        for (int e2 = 0; e2 < 8; ++e2) if (e2 != i0 && acc[e2] > v1) { v1 = acc[e2]; i1 = e2; }
        float r = expf(v1 - v0);
        float den = 1.f + r;
        toke[2 * t] = i0; toke[2 * t + 1] = i1;
        tokw[2 * t] = 1.f / den; tokw[2 * t + 1] = r / den;
    }
}

__global__ __launch_bounds__(256) void moe_count_k(const int* __restrict__ toke, int* __restrict__ counts) {
    int t = blockIdx.x * 256 + threadIdx.x;
    atomicAdd(&counts[toke[2 * t]], 1);
    atomicAdd(&counts[toke[2 * t + 1]], 1);
}

__global__ void moe_tiles_k(const int* __restrict__ counts, int* __restrict__ ntile,
                            int* __restrict__ eoff, int* __restrict__ tileE,
                            int* __restrict__ tileR, int* __restrict__ tileC) {
    if (threadIdx.x == 0 && blockIdx.x == 0) {
        int off = 0, nt = 0;
        for (int e = 0; e < NEXP; ++e) {
            eoff[e] = off;
            int c = counts[e];
            for (int r = 0; r < c; r += 128) {
                tileE[nt] = e;
                tileR[nt] = off + r;
                tileC[nt] = (c - r < 128) ? (c - r) : 128;
                ++nt;
            }
            off += c;
        }
        ntile[0] = nt;
    }
}

__global__ __launch_bounds__(256) void moe_place_k(const int* __restrict__ toke,
                                                   const float* __restrict__ tokw,
                                                   const int* __restrict__ eoff,
                                                   int* __restrict__ cursor,
                                                   int* __restrict__ rtok,
                                                   float* __restrict__ rgate,
                                                   int* __restrict__ rexp,
                                                   int* __restrict__ rowof) {
    int t = blockIdx.x * 256 + threadIdx.x;
#pragma unroll
    for (int kk = 0; kk < 2; ++kk) {
        int e = toke[2 * t + kk];
        float wv = tokw[2 * t + kk];
        int r = eoff[e] + atomicAdd(&cursor[e], 1);
        rtok[r] = t; rgate[r] = wv; rexp[r] = e;
        rowof[2 * t + kk] = r;
    }
}

/* ------------ MoE combine ------------ */
__global__ __launch_bounds__(256) void moe_combine_k(float* __restrict__ h,
                                                     const float* __restrict__ P,
                                                     const int* __restrict__ rowof,
                                                     const float* __restrict__ rgate,
                                                     const float* __restrict__ masks) {
    int t = blockIdx.x;
    int r0 = rowof[2 * t], r1 = rowof[2 * t + 1];
    float g0 = rgate[r0], g1 = rgate[r1];
    float m = masks[(t >> 11) * 4 + 3];
    float4 a = ((const float4*)(P + (size_t)r0 * DM))[threadIdx.x];
    float4 bq = ((const float4*)(P + (size_t)r1 * DM))[threadIdx.x];
    float4* h4 = (float4*)(h + (size_t)t * DM);
    float4 hv = h4[threadIdx.x];
    hv.x += m * (g0 * a.x + g1 * bq.x);
    hv.y += m * (g0 * a.y + g1 * bq.y);
    hv.z += m * (g0 * a.z + g1 * bq.z);
    hv.w += m * (g0 * a.w + g1 * bq.w);
    h4[threadIdx.x] = hv;
}

extern "C" void kernel_launch(void* const* d_in, const int* in_sizes, int n_in,
                              void* d_out, int out_size, void* d_ws, size_t ws_size,
                              hipStream_t stream) {
    const float* hidden    = (const float*)d_in[0];
    const float* router_w  = (const float*)d_in[1];
    const float* router_b  = (const float*)d_in[2];
    const float* ln_g      = (const float*)d_in[3];
    const float* ln_b      = (const float*)d_in[4];
    const float* m_win     = (const float*)d_in[5];
    const float* m_conv    = (const float*)d_in[6];
    const float* m_alog    = (const float*)d_in[7];
    const float* m_wbc     = (const float*)d_in[8];
    const float* m_wdt     = (const float*)d_in[9];
    const float* m_dtb     = (const float*)d_in[10];
    const float* m_dskip   = (const float*)d_in[11];
    const float* m_wout    = (const float*)d_in[12];
    const float* tc_theta  = (const float*)d_in[13];
    const float* tc_w      = (const float*)d_in[14];
    const float* tc_b      = (const float*)d_in[15];
    const float* w_q       = (const float*)d_in[16];
    const float* w_k       = (const float*)d_in[17];
    const float* w_v       = (const float*)d_in[18];
    const float* w_o       = (const float*)d_in[19];
    const float* wlam_cv   = (const float*)d_in[20];
    const float* moe_wg    = (const float*)d_in[21];
    const float* moe_w1    = (const float*)d_in[22];
    const float* moe_b1    = (const float*)d_in[23];
    const float* moe_w2    = (const float*)d_in[24];
    const float* moe_b2    = (const float*)d_in[25];
    float* h = (float*)d_out;
    float* w = (float*)d_ws;
    unsigned short* BIGH = (unsigned short*)(w + OFF_BIG);
    unsigned short* XCU  = (unsigned short*)(w + OFF_XC);
    unsigned short* OUTU = (unsigned short*)(w + OFF_OUT);
#define UPB(F) (BIGH + 2 * (size_t)(F))
#define UPX(F) (XCU  + 2 * (size_t)(F))
#define UPO(F) (OUTU + 2 * (size_t)(F))

    hipMemsetAsync(d_ws, 0, 2064 * sizeof(float), stream);

    pooled_k<<<dim3(4, 2, 16), 256, 0, stream>>>(hidden, w + OFF_POOLED);
    router_k<<<1, 256, 0, stream>>>(w + OFF_POOLED, router_w, router_b, w + OFF_MASKS);

    /* ---- mamba ---- */
    ln0_copy_k<<<TT, 256, 0, stream>>>(hidden, ln_g + 0 * DM, ln_b + 0 * DM, h,
                                       UPX(0), UPX(2097152), UPX(4194304));
    transb3_k<<<dim3(16, 64), 256, 0, stream>>>(m_win, UPO(0), UPO(2097152), UPX(6291456), 4096, 1024);
    mmx3_k<<<dim3(32, 32), 256, 0, stream>>>(UPX(0), UPX(2097152), UPX(4194304),
                                             UPO(0), UPO(2097152), UPX(6291456),
                                             w + OFF_BIG, 1024, 1024, 4096, 1024);
    mamba_conv_k<<<8192, 256, 0, stream>>>(w + OFF_BIG, m_conv, w + OFF_XC);
    gemmsk_f32<<<dim3(64, 2, 8), 256, 0, stream>>>(w + OFF_XC, DI, m_wbc, 128, w + OFF_LN, 128, 256);
    wbc_red_k<<<2048, 256, 0, stream>>>(w + OFF_LN, w + OFF_BC);
    scan1_k<<<dim3(8, NCH, B_SZ), 256, 0, stream>>>(w + OFF_XC, w + OFF_BC,
                                                    m_alog, m_wdt, m_dtb,
                                                    w + OFF_LN, w + OFF_PPROD);
    scan2_k<<<1024, 256, 0, stream>>>(w + OFF_LN, w + OFF_PPROD, w + OFF_OUT);
    scan3_k<<<dim3(8, NCH, B_SZ), 256, 0, stream>>>(w + OFF_XC, w + OFF_BC, w + OFF_BIG,
                                                    m_alog, m_wdt, m_dtb, m_dskip,
                                                    w + OFF_OUT);
    split3_k<<<8192, 256, 0, stream>>>(w + OFF_XC, UPB(0), UPB(4194304), UPB(8388608));
    transb3_k<<<dim3(32, 16), 256, 0, stream>>>(m_wout, UPB(12582912), UPB(13631488), UPB(14680064), 1024, 2048);
    mmx3_k<<<dim3(32, 8), 256, 0, stream>>>(UPB(0), UPB(4194304), UPB(8388608),
                                            UPB(12582912), UPB(13631488), UPB(14680064),
                                            w + OFF_OUT, 2048, 2048, 1024, 2048);
    add_ln_k<<<TT, 256, 0, stream>>>(h, w + OFF_OUT, w + OFF_MASKS, 0,
                                     ln_g + 1 * DM, ln_b + 1 * DM, w + OFF_LN,
                                     UPB(0), UPB(2097152), UPB(4194304));

    /* ---- timecrystal ---- */
    transb3_k<<<dim3(16, 16), 256, 0, stream>>>(tc_w, UPB(6291456), UPB(6815744), UPB(7340032), 1024, 1024);
    mmx3_k<<<dim3(32, 8), 256, 0, stream>>>(UPB(0), UPB(2097152), UPB(4194304),
                                            UPB(6291456), UPB(6815744), UPB(7340032),
                                            w + OFF_OUT, 1024, 1024, 1024, 1024);
    tc_ln_k<<<TT, 256, 0, stream>>>(h, w + OFF_LN, w + OFF_OUT, tc_b, tc_theta, w + OFF_MASKS,
                                    ln_g + 2 * DM, ln_b + 2 * DM, w + OFF_LN);

    /* ---- wavelet attention ---- */
    float* wdet = w + OFF_BIG;                 /* det f32 [2048][1024] at BIG 0..2M */
    wsplit_k<<<2048, 256, 0, stream>>>(w + OFF_LN, UPB(4194304), UPB(5242880), UPB(6291456), wdet);
    /* fused QKV weight planes (one launch): q/k/v at +z*1048576 elems within each plane group */
    transb3m_k<<<dim3(16, 16, 3), 256, 0, stream>>>(w_q, w_k, w_v,
                                                    UPB(7340032), UPB(8912896), UPB(10485760));
    transb3_k<<<dim3(16, 16), 256, 0, stream>>>(w_o, UPB(12058624), UPB(12582912), UPB(13107200), 1024, 1024);
    float* wqkv = w + OFF_XC;                  /* [2048][3072] f32 */
    float* wo0  = w + OFF_XC + 6291456;        /* partial half 0 */
    float* wo1  = w + OFF_OUT;                 /* partial half 1 */
    float* wml  = w + OFF_OUT + 2097152;       /* (m,l) 2x65536 */
    mmx3_k<<<dim3(16, 24), 256, 0, stream>>>(UPB(4194304), UPB(5242880), UPB(6291456),
                                             UPB(7340032), UPB(8912896), UPB(10485760),
                                             wqkv, 1024, 1024, 3072, 1024);
    wlam_attn_k<<<dim3(16, NH, B_SZ * 2), 256, 0, stream>>>(wqkv, wo0, wo1, wml);
    attn_merge_k<<<2048, 256, 0, stream>>>(wo0, wo1, wml,
                                           UPB(13631488), UPB(14680064), UPB(15728640));
    mmx3_k<<<dim3(16, 8), 256, 0, stream>>>(UPB(13631488), UPB(14680064), UPB(15728640),
                                            UPB(12058624), UPB(12582912), UPB(13107200),
                                            w + OFF_OUT, 1024, 1024, 1024, 1024);
    wpost_ln_k<<<TT, 256, 0, stream>>>(h, w + OFF_OUT, wdet, wlam_cv, w + OFF_MASKS,
                                       ln_g + 3 * DM, ln_b + 3 * DM, w + OFF_LN,
                                       UPB(MB_LNB));

    /* ---- MoE: fp32 gate + bf16 MFMA experts ---- */
    moe_gate_k<<<1024, 256, 0, stream>>>(w + OFF_LN, moe_wg, (int*)(w + OFF_TOKE), w + OFF_TOKW);
    moe_count_k<<<16, 256, 0, stream>>>((const int*)(w + OFF_TOKE), (int*)(w + OFF_COUNTS));
    moe_tiles_k<<<1, 64, 0, stream>>>((const int*)(w + OFF_COUNTS), (int*)(w + OFF_NTILE),
                                      (int*)(w + OFF_EOFF), (int*)(w + OFF_TILEE),
                                      (int*)(w + OFF_TILER), (int*)(w + OFF_TILEC));
    moe_place_k<<<16, 256, 0, stream>>>((const int*)(w + OFF_TOKE), w + OFF_TOKW,
                                        (const int*)(w + OFF_EOFF), (int*)(w + OFF_CURSOR),
                                        (int*)(w + OFF_RTOK), w + OFF_RGATE,
                                        (int*)(w + OFF_REXP), (int*)(w + OFF_ROWOF));
    for (int ci = 0; ci < 4; ++ci) {
        transb2_k<<<dim3(16, 16, 16), 256, 0, stream>>>(moe_w1 + (size_t)ci * CHK,
                                                        moe_w2 + (size_t)ci * CHK * DM,
                                                        UPB(MB_W1T), UPB(MB_W2T));
        mm_k<2><<<dim3(MAXTILE, 8), 256, 0, stream>>>(UPB(MB_LNB), UPB(MB_W1T), UPB(MB_HB),
                                                      1024, 1024, 1024, 1024,
                                                      moe_b1, ci * CHK,
                                                      (const int*)(w + OFF_NTILE), (const int*)(w + OFF_TILEE),
                                                      (const int*)(w + OFF_TILER), (const int*)(w + OFF_TILEC),
                                                      (const int*)(w + OFF_RTOK));
        if (ci == 0) {
            mm_k<4><<<dim3(MAXTILE, 8), 256, 0, stream>>>(UPB(MB_HB), UPB(MB_W2T),
                                                          w + OFF_XC, 1024, 1024, 1024, 1024,
                                                          moe_b2, 0,
                                                          (const int*)(w + OFF_NTILE), (const int*)(w + OFF_TILEE),
                                                          (const int*)(w + OFF_TILER), (const int*)(w + OFF_TILEC),
                                                          nullptr);
        } else {
            mm_k<3><<<dim3(MAXTILE, 8), 256, 0, stream>>>(UPB(MB_HB), UPB(MB_W2T),
                                                          w + OFF_XC, 1024, 1024, 1024, 1024,
                                                          nullptr, 0,
                                                          (const int*)(w + OFF_NTILE), (const int*)(w + OFF_TILEE),
                                                          (const int*)(w + OFF_TILER), (const int*)(w + OFF_TILEC),
                                                          nullptr);
        }
    }
    moe_combine_k<<<4096, 256, 0, stream>>>(h, w + OFF_XC, (const int*)(w + OFF_ROWOF),
                                            w + OFF_RGATE, w + OFF_MASKS);
#undef UPB
#undef UPX
#undef UPO
}

// Round 14
// 1595.607 us; speedup vs baseline: 1.0169x; 1.0169x over previous
//
#include <hip/hip_runtime.h>
#include <math.h>

#define S_LEN   2048
#define B_SZ    2
#define DM      1024
#define DI      2048
#define NST     64
#define LH      1024
#define NH      16
#define HD      64
#define TT      4096      /* B*S tokens */
#define NEXP    8
#define FF      4096
#define CHK     1024      /* MoE FF chunk */
#define MAXTILE 72
#define INVR2   0.7071067811865476f
#define CHUNK   128       /* scan chunk length */
#define NCH     16        /* S_LEN / CHUNK */

/* ---- workspace layout (offsets in floats) ---- */
#define OFF_POOLED 0
#define OFF_COUNTS 2048
#define OFF_CURSOR 2056
#define OFF_MASKS  2064
#define OFF_NTILE  2072
#define OFF_EOFF   2080
#define OFF_TILEE  2112
#define OFF_TILER  2272
#define OFF_TILEC  2432
#define OFF_TOKE   2592
#define OFF_TOKW   10784
#define OFF_RTOK   18976
#define OFF_RGATE  27168
#define OFF_REXP   35360
#define OFF_ROWOF  43552
#define OFF_LN     65536                       /* 4M f ; hend during scan ; wbc partials */
#define OFF_BIG    (OFF_LN + 4194304)          /* 16M f : phase-multiplexed */
#define OFF_XC     (OFF_BIG + 16777216)        /* 8454144 f */
#define OFF_PPROD  (OFF_XC + 8388608)          /* 65536 f slack of XC */
#define OFF_BC     (OFF_XC + 8454144)          /* 524288 f */
#define OFF_OUT    (OFF_BC + 524288)           /* 4M f */
/* total = 34,209,792 floats = ~130.5 MiB (proven) */

/* MoE-phase BIG sub-offsets (floats) */
#define MB_HB   0
#define MB_W1T  4194304
#define MB_W2T  8388608
#define MB_LNB  12582912

typedef __attribute__((ext_vector_type(8))) short bf8_t;
typedef __attribute__((ext_vector_type(4))) float f4_t;

__device__ inline float b2f(unsigned short u) {
    unsigned v = (unsigned)u << 16; float f; __builtin_memcpy(&f, &v, 4); return f;
}
__device__ inline unsigned short f2b(float f) {
    unsigned u; __builtin_memcpy(&u, &f, 4);
    unsigned r = (u + 0x7fffu + ((u >> 16) & 1u)) >> 16;
    return (unsigned short)r;
}
__device__ inline void split3v(float v, unsigned short& h, unsigned short& m, unsigned short& l) {
    h = f2b(v);
    float t = v - b2f(h);
    m = f2b(t);
    float t2 = t - b2f(m);
    l = f2b(t2);
}
__device__ inline void split3q(float4 v, ushort4& h4, ushort4& m4, ushort4& l4) {
    split3v(v.x, h4.x, m4.x, l4.x);
    split3v(v.y, h4.y, m4.y, l4.y);
    split3v(v.z, h4.z, m4.z, l4.z);
    split3v(v.w, h4.w, m4.w, l4.w);
}
__device__ inline float gelu_tanh(float x) {
    float x3 = x * x * x;
    return 0.5f * x * (1.f + tanhf(0.7978845608028654f * (x + 0.044715f * x3)));
}
__device__ inline void gld16(const void* g, void* l) {
    __builtin_amdgcn_global_load_lds((const __attribute__((address_space(1))) void*)g,
                                     (__attribute__((address_space(3))) void*)l, 16, 0, 0);
}

/* block-wide (256 thr) LayerNorm of one row held as float4/thread */
__device__ inline float4 row_ln(float4 v, const float* __restrict__ g,
                                const float* __restrict__ bta) {
    float s1 = v.x + v.y + v.z + v.w;
    float s2 = v.x * v.x + v.y * v.y + v.z * v.z + v.w * v.w;
#pragma unroll
    for (int off = 32; off; off >>= 1) {
        s1 += __shfl_xor(s1, off);
        s2 += __shfl_xor(s2, off);
    }
    __shared__ float sh1[4], sh2[4];
    int w = threadIdx.x >> 6, lane = threadIdx.x & 63;
    if (lane == 0) { sh1[w] = s1; sh2[w] = s2; }
    __syncthreads();
    float t1 = sh1[0] + sh1[1] + sh1[2] + sh1[3];
    float t2 = sh2[0] + sh2[1] + sh2[2] + sh2[3];
    float mean = t1 * (1.f / 1024.f);
    float var = t2 * (1.f / 1024.f) - mean * mean;
    float rs = rsqrtf(var + 1e-6f);
    float4 gv = ((const float4*)g)[threadIdx.x];
    float4 bv = ((const float4*)bta)[threadIdx.x];
    float4 o;
    o.x = (v.x - mean) * rs * gv.x + bv.x;
    o.y = (v.y - mean) * rs * gv.y + bv.y;
    o.z = (v.z - mean) * rs * gv.z + bv.z;
    o.w = (v.w - mean) * rs * gv.w + bv.w;
    return o;
}

/* ------------ pooled mean over sequence ------------ */
__global__ __launch_bounds__(256) void pooled_k(const float* __restrict__ h0, float* __restrict__ pooled) {
    int d = blockIdx.x * 256 + threadIdx.x;
    int b = blockIdx.y, sc = blockIdx.z;
    float s = 0.f;
    for (int i = 0; i < 128; ++i) {
        int ss = sc * 128 + i;
        s += h0[((size_t)(b * S_LEN + ss)) * DM + d];
    }
    atomicAdd(&pooled[b * DM + d], s * (1.f / 2048.f));
}

/* ------------ router: masks ------------ */
__global__ __launch_bounds__(256) void router_k(const float* __restrict__ pooled,
                                                const float* __restrict__ rw,
                                                const float* __restrict__ rb,
                                                float* __restrict__ masks) {
    int tid = threadIdx.x;
    float p[8] = {0, 0, 0, 0, 0, 0, 0, 0};
    for (int d = tid; d < DM; d += 256) {
        float p0 = pooled[d], p1 = pooled[DM + d];
        float4 w4 = *(const float4*)(rw + (size_t)d * 4);
        p[0] += p0 * w4.x; p[1] += p0 * w4.y; p[2] += p0 * w4.z; p[3] += p0 * w4.w;
        p[4] += p1 * w4.x; p[5] += p1 * w4.y; p[6] += p1 * w4.z; p[7] += p1 * w4.w;
    }
#pragma unroll
    for (int off = 32; off; off >>= 1) {
#pragma unroll
        for (int j = 0; j < 8; ++j) p[j] += __shfl_xor(p[j], off);
    }
    __shared__ float sh[4][8];
    int w = tid >> 6, lane = tid & 63;
    if (lane == 0) {
#pragma unroll
        for (int j = 0; j < 8; ++j) sh[w][j] = p[j];
    }
    __syncthreads();
    if (tid < 8) {
        float v = sh[0][tid] + sh[1][tid] + sh[2][tid] + sh[3][tid] + rb[tid & 3];
        float sc = 1.f / (1.f + expf(-v));
        masks[tid] = (sc > 0.3f) ? 1.f : 0.f;
    }
}

/* ------------ fused: h = hidden (copy) + LN0 -> bf16x3 planes ------------ */
__global__ __launch_bounds__(256) void ln0_copy_k(const float* __restrict__ hid,
                                                  const float* __restrict__ g,
                                                  const float* __restrict__ bta,
                                                  float* __restrict__ hout,
                                                  unsigned short* __restrict__ ph,
                                                  unsigned short* __restrict__ pm,
                                                  unsigned short* __restrict__ pl) {
    int row = blockIdx.x;
    float4 v = ((const float4*)(hid + (size_t)row * DM))[threadIdx.x];
    ((float4*)(hout + (size_t)row * DM))[threadIdx.x] = v;
    float4 o = row_ln(v, g, bta);
    ushort4 h4, m4, l4;
    split3q(o, h4, m4, l4);
    size_t f = (size_t)row * 256 + threadIdx.x;
    ((ushort4*)ph)[f] = h4;
    ((ushort4*)pm)[f] = m4;
    ((ushort4*)pl)[f] = l4;
}

/* ------------ fused: h += mask*src ; LN -> fp32 + bf16x3 planes ------------ */
__global__ __launch_bounds__(256) void add_ln_k(float* __restrict__ h,
                                                const float* __restrict__ src,
                                                const float* __restrict__ masks, int midx,
                                                const float* __restrict__ g,
                                                const float* __restrict__ bta,
                                                float* __restrict__ out,
                                                unsigned short* __restrict__ ph,
                                                unsigned short* __restrict__ pm,
                                                unsigned short* __restrict__ pl) {
    int row = blockIdx.x;
    int b = row >> 11;
    float m = masks[b * 4 + midx];
    float4 hv = ((float4*)(h + (size_t)row * DM))[threadIdx.x];
    float4 sv = ((const float4*)(src + (size_t)row * DM))[threadIdx.x];
    hv.x += m * sv.x; hv.y += m * sv.y; hv.z += m * sv.z; hv.w += m * sv.w;
    ((float4*)(h + (size_t)row * DM))[threadIdx.x] = hv;
    float4 o = row_ln(hv, g, bta);
    ((float4*)(out + (size_t)row * DM))[threadIdx.x] = o;
    ushort4 h4, m4, l4;
    split3q(o, h4, m4, l4);
    size_t f = (size_t)row * 256 + threadIdx.x;
    ((ushort4*)ph)[f] = h4;
    ((ushort4*)pm)[f] = m4;
    ((ushort4*)pl)[f] = l4;
}

/* ------------ fused: timecrystal elementwise ; LN (fp32 out, may alias ln) ------------ */
__global__ __launch_bounds__(256) void tc_ln_k(float* __restrict__ h,
                                               const float* __restrict__ ln,
                                               const float* __restrict__ gm,
                                               const float* __restrict__ tcb,
                                               const float* __restrict__ theta,
                                               const float* __restrict__ masks,
                                               const float* __restrict__ g,
                                               const float* __restrict__ bta,
                                               float* __restrict__ out) {
    int row = blockIdx.x;
    int b = row >> 11;
    float th = theta[0];
    float ct = cosf(th), st = sinf(th);
    float m = masks[b * 4 + 1];
    float4 xv = ((const float4*)(ln + (size_t)row * DM))[threadIdx.x];
    float4 gv = ((const float4*)(gm + (size_t)row * DM))[threadIdx.x];
    float4 bb = ((const float4*)tcb)[threadIdx.x];
    float4 hv = ((float4*)(h + (size_t)row * DM))[threadIdx.x];
    hv.x += m * (ct * xv.x + st * tanhf(gv.x + bb.x));
    hv.y += m * (ct * xv.y + st * tanhf(gv.y + bb.y));
    hv.z += m * (ct * xv.z + st * tanhf(gv.z + bb.z));
    hv.w += m * (ct * xv.w + st * tanhf(gv.w + bb.w));
    ((float4*)(h + (size_t)row * DM))[threadIdx.x] = hv;
    float4 o = row_ln(hv, g, bta);
    ((float4*)(out + (size_t)row * DM))[threadIdx.x] = o;
}

/* ------------ fused: wavelet merge + dwconv + masked add ; LN -> fp32 + bf16 cast ------------ */
__global__ __launch_bounds__(256) void wpost_ln_k(float* __restrict__ h,
                                                  const float* __restrict__ o2,
                                                  const float* __restrict__ det,
                                                  const float* __restrict__ wconv,
                                                  const float* __restrict__ masks,
                                                  const float* __restrict__ g,
                                                  const float* __restrict__ bta,
                                                  float* __restrict__ out,
                                                  unsigned short* __restrict__ outb) {
    int row = blockIdx.x;
    int s = row & 2047;
    int b = row >> 11;
    float m = masks[b * 4 + 2];
    float4 acc = {0.f, 0.f, 0.f, 0.f};
#pragma unroll
    for (int t = 0; t < 4; ++t) {
        int ss = s + t - 2;
        if (ss >= 0 && ss < S_LEN) {
            int l = ss >> 1;
            size_t lr = (size_t)(b * LH + l) * DM;
            float4 ov = ((const float4*)(o2 + lr))[threadIdx.x];
            float4 dv = ((const float4*)(det + lr))[threadIdx.x];
            float sg = (ss & 1) ? -INVR2 : INVR2;
            float4 wv = ((const float4*)(wconv + (size_t)t * DM))[threadIdx.x];
            acc.x = fmaf(wv.x, INVR2 * ov.x + sg * dv.x, acc.x);
            acc.y = fmaf(wv.y, INVR2 * ov.y + sg * dv.y, acc.y);
            acc.z = fmaf(wv.z, INVR2 * ov.z + sg * dv.z, acc.z);
            acc.w = fmaf(wv.w, INVR2 * ov.w + sg * dv.w, acc.w);
        }
    }
    float4 hv = ((float4*)(h + (size_t)row * DM))[threadIdx.x];
    hv.x += m * acc.x; hv.y += m * acc.y; hv.z += m * acc.z; hv.w += m * acc.w;
    ((float4*)(h + (size_t)row * DM))[threadIdx.x] = hv;
    float4 o = row_ln(hv, g, bta);
    ((float4*)(out + (size_t)row * DM))[threadIdx.x] = o;
    ushort4 ob;
    ob.x = f2b(o.x); ob.y = f2b(o.y); ob.z = f2b(o.z); ob.w = f2b(o.w);
    ((ushort4*)(outb))[(size_t)row * 256 + threadIdx.x] = ob;
}

/* ------------ split fp32 -> 3 bf16 planes (same layout) ------------ */
__global__ __launch_bounds__(256) void split3_k(const float* __restrict__ in,
                                                unsigned short* __restrict__ ph,
                                                unsigned short* __restrict__ pm,
                                                unsigned short* __restrict__ pl) {
    size_t f = (size_t)blockIdx.x * 256 + threadIdx.x;
    float4 v = ((const float4*)in)[f];
    ushort4 hh, mm, ll;
    split3q(v, hh, mm, ll);
    ((ushort4*)ph)[f] = hh;
    ((ushort4*)pm)[f] = mm;
    ((ushort4*)pl)[f] = ll;
}

/* ------------ transpose fp32 [K][N] -> 3 bf16 [N][K] planes ------------ */
__global__ __launch_bounds__(256) void transb3_k(const float* __restrict__ in,
                                                 unsigned short* __restrict__ oh,
                                                 unsigned short* __restrict__ om,
                                                 unsigned short* __restrict__ ol,
                                                 int ldi, int ldo) {
    __shared__ float t[64][65];
    const int tid = threadIdx.x;
    const int k0 = blockIdx.x << 6, n0 = blockIdx.y << 6;
    const int rr = tid >> 4, cc = (tid & 15) << 2;
#pragma unroll
    for (int i = 0; i < 4; ++i) {
        float4 v = *(const float4*)(in + (size_t)(k0 + rr + i * 16) * ldi + n0 + cc);
        *(float4*)&t[rr + i * 16][cc] = v;
    }
    __syncthreads();
#pragma unroll
    for (int i = 0; i < 4; ++i) {
        int n = rr + i * 16;
        ushort4 h4, m4, l4;
        split3v(t[cc + 0][n], h4.x, m4.x, l4.x);
        split3v(t[cc + 1][n], h4.y, m4.y, l4.y);
        split3v(t[cc + 2][n], h4.z, m4.z, l4.z);
        split3v(t[cc + 3][n], h4.w, m4.w, l4.w);
        size_t of = (size_t)(n0 + n) * ldo + k0 + cc;
        *(ushort4*)(oh + of) = h4;
        *(ushort4*)(om + of) = m4;
        *(ushort4*)(ol + of) = l4;
    }
}

/* ------------ transb3 multi-source (QKV): z picks src; dst offset z*1048576 elems ------------ */
__global__ __launch_bounds__(256) void transb3m_k(const float* __restrict__ s0,
                                                  const float* __restrict__ s1,
                                                  const float* __restrict__ s2,
                                                  unsigned short* __restrict__ oh,
                                                  unsigned short* __restrict__ om,
                                                  unsigned short* __restrict__ ol) {
    __shared__ float t[64][65];
    const int tid = threadIdx.x;
    const int z = blockIdx.z;
    const float* in = (z == 0) ? s0 : ((z == 1) ? s1 : s2);
    size_t doff = (size_t)z * 1048576;   /* 1024x1024 bf16 elements per source */
    const int k0 = blockIdx.x << 6, n0 = blockIdx.y << 6;
    const int rr = tid >> 4, cc = (tid & 15) << 2;
#pragma unroll
    for (int i = 0; i < 4; ++i) {
        float4 v = *(const float4*)(in + (size_t)(k0 + rr + i * 16) * 1024 + n0 + cc);
        *(float4*)&t[rr + i * 16][cc] = v;
    }
    __syncthreads();
#pragma unroll
    for (int i = 0; i < 4; ++i) {
        int n = rr + i * 16;
        ushort4 h4, m4, l4;
        split3v(t[cc + 0][n], h4.x, m4.x, l4.x);
        split3v(t[cc + 1][n], h4.y, m4.y, l4.y);
        split3v(t[cc + 2][n], h4.z, m4.z, l4.z);
        split3v(t[cc + 3][n], h4.w, m4.w, l4.w);
        size_t of = doff + (size_t)(n0 + n) * 1024 + k0 + cc;
        *(ushort4*)(oh + of) = h4;
        *(ushort4*)(om + of) = m4;
        *(ushort4*)(ol + of) = l4;
    }
}

/* ------------ MoE dual transpose: z<8 -> w1 chunk (ldi 4096), z>=8 -> w2 chunk (ldi 1024) ------------ */
__global__ __launch_bounds__(256) void transb2_k(const float* __restrict__ in1,
                                                 const float* __restrict__ in2,
                                                 unsigned short* __restrict__ out1,
                                                 unsigned short* __restrict__ out2) {
    __shared__ float t[64][65];
    const int tid = threadIdx.x;
    const int z = blockIdx.z;
    const float* in;
    unsigned short* out;
    int ldi;
    if (z < 8) { in = in1 + (size_t)z * 4194304; out = out1 + (size_t)z * 1048576; ldi = 4096; }
    else       { in = in2 + (size_t)(z - 8) * 4194304; out = out2 + (size_t)(z - 8) * 1048576; ldi = 1024; }
    const int k0 = blockIdx.x << 6, n0 = blockIdx.y << 6;
    const int rr = tid >> 4, cc = (tid & 15) << 2;
#pragma unroll
    for (int i = 0; i < 4; ++i) {
        float4 v = *(const float4*)(in + (size_t)(k0 + rr + i * 16) * ldi + n0 + cc);
        *(float4*)&t[rr + i * 16][cc] = v;
    }
    __syncthreads();
#pragma unroll
    for (int i = 0; i < 4; ++i) {
        int n = rr + i * 16;
        ushort4 o;
        o.x = f2b(t[cc + 0][n]); o.y = f2b(t[cc + 1][n]);
        o.z = f2b(t[cc + 2][n]); o.w = f2b(t[cc + 3][n]);
        *(ushort4*)(out + (size_t)(n0 + n) * 1024 + k0 + cc) = o;
    }
}

/* ------------ bf16x3 exact-fp32 MFMA GEMM: C = A @ Bt^T, 128x128 tile, BK=32 ------------ */
__global__ __launch_bounds__(256) void mmx3_k(const unsigned short* __restrict__ Ah,
                                              const unsigned short* __restrict__ Am,
                                              const unsigned short* __restrict__ Al,
                                              const unsigned short* __restrict__ Bh,
                                              const unsigned short* __restrict__ Bm,
                                              const unsigned short* __restrict__ Bl,
                                              float* __restrict__ C,
                                              int lda, int ldb, int ldc, int K) {
    __shared__ unsigned short S[6][4096];   /* 6 planes x [128 rows][32 k], 48 KB */
    const int tid = threadIdx.x;
    const int m0 = (int)blockIdx.x << 7, n0 = (int)blockIdx.y << 7;
    size_t aoff[2], boff[2];
    int dst[2];
#pragma unroll
    for (int c = 0; c < 2; ++c) {
        int idx = tid + (c << 8);
        int r = idx >> 2, sd = idx & 3;
        int ks = (sd ^ (r & 3)) << 3;
        aoff[c] = (size_t)(m0 + r) * lda + ks;
        boff[c] = (size_t)(n0 + r) * ldb + ks;
        dst[c] = idx << 3;
    }
    const int lane = tid & 63;
    const int w = tid >> 6, wr = w >> 1, wc = w & 1;
    const int lrow = lane & 15, lgrp = lane >> 4;
    f4_t acc[4][4];
#pragma unroll
    for (int i = 0; i < 4; ++i)
#pragma unroll
        for (int j = 0; j < 4; ++j) acc[i][j] = (f4_t){0.f, 0.f, 0.f, 0.f};
    int ard[4], brd[4];
#pragma unroll
    for (int t4 = 0; t4 < 4; ++t4) {
        int ra = wr * 64 + t4 * 16 + lrow;
        ard[t4] = ra * 32 + ((lgrp ^ (ra & 3)) << 3);
        int rb = wc * 64 + t4 * 16 + lrow;
        brd[t4] = rb * 32 + ((lgrp ^ (rb & 3)) << 3);
    }
    for (int k0 = 0; k0 < K; k0 += 32) {
        __syncthreads();
#pragma unroll
        for (int c = 0; c < 2; ++c) {
            gld16(Ah + aoff[c] + k0, &S[0][dst[c]]);
            gld16(Am + aoff[c] + k0, &S[1][dst[c]]);
            gld16(Al + aoff[c] + k0, &S[2][dst[c]]);
            gld16(Bh + boff[c] + k0, &S[3][dst[c]]);
            gld16(Bm + boff[c] + k0, &S[4][dst[c]]);
            gld16(Bl + boff[c] + k0, &S[5][dst[c]]);
        }
        __syncthreads();
        bf8_t ah4[4], am4[4], al4[4];
#pragma unroll
        for (int t4 = 0; t4 < 4; ++t4) {
            ah4[t4] = *(const bf8_t*)&S[0][ard[t4]];
            am4[t4] = *(const bf8_t*)&S[1][ard[t4]];
            al4[t4] = *(const bf8_t*)&S[2][ard[t4]];
        }
#pragma unroll
        for (int ni = 0; ni < 4; ++ni) {
            bf8_t bh = *(const bf8_t*)&S[3][brd[ni]];
            bf8_t bm = *(const bf8_t*)&S[4][brd[ni]];
            bf8_t bl = *(const bf8_t*)&S[5][brd[ni]];
#pragma unroll
            for (int mi = 0; mi < 4; ++mi) {
                acc[mi][ni] = __builtin_amdgcn_mfma_f32_16x16x32_bf16(ah4[mi], bh, acc[mi][ni], 0, 0, 0);
                acc[mi][ni] = __builtin_amdgcn_mfma_f32_16x16x32_bf16(am4[mi], bh, acc[mi][ni], 0, 0, 0);
                acc[mi][ni] = __builtin_amdgcn_mfma_f32_16x16x32_bf16(al4[mi], bh, acc[mi][ni], 0, 0, 0);
                acc[mi][ni] = __builtin_amdgcn_mfma_f32_16x16x32_bf16(ah4[mi], bm, acc[mi][ni], 0, 0, 0);
                acc[mi][ni] = __builtin_amdgcn_mfma_f32_16x16x32_bf16(am4[mi], bm, acc[mi][ni], 0, 0, 0);
                acc[mi][ni] = __builtin_amdgcn_mfma_f32_16x16x32_bf16(ah4[mi], bl, acc[mi][ni], 0, 0, 0);
            }
        }
    }
#pragma unroll
    for (int mi = 0; mi < 4; ++mi) {
#pragma unroll
        for (int j = 0; j < 4; ++j) {
            int rr = wr * 64 + mi * 16 + lgrp * 4 + j;
#pragma unroll
            for (int ni = 0; ni < 4; ++ni) {
                int col = n0 + wc * 64 + ni * 16 + lrow;
                C[(size_t)(m0 + rr) * ldc + col] = acc[mi][ni][j];
            }
        }
    }
}

/* ------------ MFMA GEMM (MoE experts): MODE 2 gemm1, 3 gemm2 accum, 4 gemm2 init+bias2 ------------ */
template<int MODE>
__global__ __launch_bounds__(256) void mm_k(const unsigned short* __restrict__ A,
                                            const unsigned short* __restrict__ Bt,
                                            void* __restrict__ Cv,
                                            int lda, int ldb, int ldc, int K,
                                            const float* __restrict__ bias, int fofs,
                                            const int* __restrict__ ntile,
                                            const int* __restrict__ tileE,
                                            const int* __restrict__ tileR,
                                            const int* __restrict__ tileC,
                                            const int* __restrict__ rtok) {
    __shared__ unsigned short As[8192];
    __shared__ unsigned short Bs[8192];
    const int tid = threadIdx.x;
    int m0 = 0;
    const int n0 = (int)blockIdx.y << 7;
    int cnt = 128, e = 0, row0 = 0;
    if constexpr (MODE >= 2) {
        if ((int)blockIdx.x >= ntile[0]) return;
        e = tileE[blockIdx.x]; row0 = tileR[blockIdx.x]; cnt = tileC[blockIdx.x];
    } else {
        m0 = (int)blockIdx.x << 7;
    }
    const unsigned short* Bp = Bt;
    if constexpr (MODE >= 2) Bp += (size_t)e << 20;
    size_t aoff[4], boff[4];
#pragma unroll
    for (int c = 0; c < 4; ++c) {
        int r = (tid >> 3) + 32 * c;
        int ks = ((tid & 7) ^ (r & 7)) << 3;
        int gr;
        if constexpr (MODE == 2)      gr = rtok[row0 + (r < cnt ? r : cnt - 1)];
        else if constexpr (MODE >= 3) gr = row0 + (r < cnt ? r : cnt - 1);
        else                          gr = m0 + r;
        aoff[c] = (size_t)gr * lda + ks;
        boff[c] = (size_t)(n0 + r) * ldb + ks;
    }
    const int lane = tid & 63;
    const int w = tid >> 6, wr = w >> 1, wc = w & 1;
    const int lrow = lane & 15, lgrp = lane >> 4;
    f4_t acc[4][4];
#pragma unroll
    for (int i = 0; i < 4; ++i)
#pragma unroll
        for (int j = 0; j < 4; ++j) acc[i][j] = (f4_t){0.f, 0.f, 0.f, 0.f};
    int ard[4][2], brd[4][2];
#pragma unroll
    for (int t4 = 0; t4 < 4; ++t4)
#pragma unroll
        for (int kk = 0; kk < 2; ++kk) {
            int ra = wr * 64 + t4 * 16 + lrow;
            ard[t4][kk] = ra * 64 + (((lgrp + (kk << 2)) ^ (ra & 7)) << 3);
            int rb = wc * 64 + t4 * 16 + lrow;
            brd[t4][kk] = rb * 64 + (((lgrp + (kk << 2)) ^ (rb & 7)) << 3);
        }
    for (int k0 = 0; k0 < K; k0 += 64) {
        __syncthreads();
#pragma unroll
        for (int c = 0; c < 4; ++c)
            gld16(A + aoff[c] + k0, As + c * 2048 + tid * 8);
#pragma unroll
        for (int c = 0; c < 4; ++c)
            gld16(Bp + boff[c] + k0, Bs + c * 2048 + tid * 8);
        __syncthreads();
        bf8_t af[4][2], bfv[4][2];
#pragma unroll
        for (int t4 = 0; t4 < 4; ++t4) {
            af[t4][0]  = *(const bf8_t*)&As[ard[t4][0]];
            af[t4][1]  = *(const bf8_t*)&As[ard[t4][1]];
            bfv[t4][0] = *(const bf8_t*)&Bs[brd[t4][0]];
            bfv[t4][1] = *(const bf8_t*)&Bs[brd[t4][1]];
        }
#pragma unroll
        for (int mi = 0; mi < 4; ++mi)
#pragma unroll
            for (int ni = 0; ni < 4; ++ni) {
                acc[mi][ni] = __builtin_amdgcn_mfma_f32_16x16x32_bf16(af[mi][0], bfv[ni][0], acc[mi][ni], 0, 0, 0);
                acc[mi][ni] = __builtin_amdgcn_mfma_f32_16x16x32_bf16(af[mi][1], bfv[ni][1], acc[mi][ni], 0, 0, 0);
            }
    }
#pragma unroll
    for (int mi = 0; mi < 4; ++mi) {
#pragma unroll
        for (int j = 0; j < 4; ++j) {
            int lr = wr * 64 + mi * 16 + lgrp * 4 + j;
            if constexpr (MODE >= 2) { if (lr >= cnt) continue; }
#pragma unroll
            for (int ni = 0; ni < 4; ++ni) {
                int col = n0 + wc * 64 + ni * 16 + lrow;
                float vv = acc[mi][ni][j];
                if constexpr (MODE == 0) {
                    ((float*)Cv)[(size_t)(m0 + lr) * ldc + col] = vv;
                } else if constexpr (MODE == 1) {
                    ((unsigned short*)Cv)[(size_t)(m0 + lr) * ldc + col] = f2b(vv);
                } else if constexpr (MODE == 2) {
                    float bz = bias[(size_t)e * FF + fofs + col];
                    ((unsigned short*)Cv)[(size_t)(row0 + lr) * ldc + col] = f2b(gelu_tanh(vv + bz));
                } else if constexpr (MODE == 3) {
                    ((float*)Cv)[(size_t)(row0 + lr) * ldc + col] += vv;
                } else { /* MODE 4: init with expert output bias b2 */
                    ((float*)Cv)[(size_t)(row0 + lr) * ldc + col] = vv + bias[(size_t)e * DM + col];
                }
            }
        }
    }
}

/* ------------ split-K fp32 GEMM for wbc ------------ */
__global__ __launch_bounds__(256) void gemmsk_f32(const float* __restrict__ A, int lda,
                                                  const float* __restrict__ B, int ldb,
                                                  float* __restrict__ P, int ldc, int Kslab) {
    __shared__ float As[16][68];
    __shared__ float Bs[16][68];
    const int tid = threadIdx.x;
    const int tx = tid & 15, ty = tid >> 4;
    const int m0 = blockIdx.x * 64, n0 = blockIdx.y * 64;
    const int kbeg = blockIdx.z * Kslab, kend = kbeg + Kslab;
    P += (size_t)blockIdx.z * 4096 * 128;
    const int la_r = tid >> 2, la_k = (tid & 3) << 2;
    const int lb_r = tid >> 4, lb_n = (tid & 15) << 2;
    float acc[4][4] = {};
    for (int k0 = kbeg; k0 < kend; k0 += 16) {
        float4 av = *(const float4*)(A + (size_t)(m0 + la_r) * lda + k0 + la_k);
        float4 bv = *(const float4*)(B + (size_t)(k0 + lb_r) * ldb + n0 + lb_n);
        __syncthreads();
        As[la_k + 0][la_r] = av.x; As[la_k + 1][la_r] = av.y;
        As[la_k + 2][la_r] = av.z; As[la_k + 3][la_r] = av.w;
        *(float4*)&Bs[lb_r][lb_n] = bv;
        __syncthreads();
#pragma unroll
        for (int kk = 0; kk < 16; ++kk) {
            float4 a4 = *(const float4*)&As[kk][ty << 2];
            float4 b4 = *(const float4*)&Bs[kk][tx << 2];
            float aa[4] = {a4.x, a4.y, a4.z, a4.w};
            float bb[4] = {b4.x, b4.y, b4.z, b4.w};
#pragma unroll
            for (int i = 0; i < 4; ++i)
#pragma unroll
                for (int j = 0; j < 4; ++j)
                    acc[i][j] = fmaf(aa[i], bb[j], acc[i][j]);
        }
    }
#pragma unroll
    for (int i = 0; i < 4; ++i) {
        int m = m0 + (ty << 2) + i;
        float4 o;
        o.x = acc[i][0]; o.y = acc[i][1]; o.z = acc[i][2]; o.w = acc[i][3];
        *(float4*)(P + (size_t)m * ldc + n0 + (tx << 2)) = o;
    }
}

/* ------------ reduce 8 wbc partials (deterministic order) ------------ */
__global__ __launch_bounds__(256) void wbc_red_k(const float* __restrict__ part,
                                                 float* __restrict__ bc) {
    size_t i = (size_t)blockIdx.x * 256 + threadIdx.x;
    float s = 0.f;
#pragma unroll
    for (int z = 0; z < 8; ++z) s += part[(size_t)z * 524288 + i];
    bc[i] = s;
}

/* ------------ mamba causal dwconv + silu (4 s-positions per thread) ------------ */
__global__ __launch_bounds__(256) void mamba_conv_k(const float* __restrict__ xz,
                                                    const float* __restrict__ cw,
                                                    float* __restrict__ xc) {
    size_t i = (size_t)blockIdx.x * 256 + threadIdx.x;   /* over TT*DI/4 = 2M */
    int c = (int)(i & (DI - 1));
    size_t g = i >> 11;
    int sg = (int)(g & 511);
    int b = (int)(g >> 9);
    int s0 = sg << 2;
    const float* base = xz + ((size_t)b * S_LEN) * 4096 + c;
    float x[7];
#pragma unroll
    for (int t = 0; t < 7; ++t) {
        int ss = s0 - 3 + t;
        x[t] = (ss >= 0) ? base[(size_t)ss * 4096] : 0.f;
    }
    float w0 = cw[0 * DI + c], w1 = cw[1 * DI + c];
    float w2 = cw[2 * DI + c], w3 = cw[3 * DI + c];
    float* out = xc + ((size_t)(b * S_LEN + s0)) * DI + c;
#pragma unroll
    for (int j = 0; j < 4; ++j) {
        float acc = 0.f;
        acc = fmaf(w0, x[j + 0], acc);
        acc = fmaf(w1, x[j + 1], acc);
        acc = fmaf(w2, x[j + 2], acc);
        acc = fmaf(w3, x[j + 3], acc);
        float sg2 = 1.f / (1.f + expf(-acc));
        out[(size_t)j * DI] = acc * sg2;
    }
}

/* ------------ mamba chunked scan, pass 1 ------------ */
__global__ __launch_bounds__(256) void scan1_k(const float* __restrict__ xc,
                                               const float* __restrict__ bc,
                                               const float* __restrict__ alog,
                                               const float* __restrict__ wdt,
                                               const float* __restrict__ dtb,
                                               float* __restrict__ hend,
                                               float* __restrict__ pprod) {
    const int b = blockIdx.z, k = blockIdx.y;
    const int c = blockIdx.x * 256 + threadIdx.x;
    __shared__ float Bs[CHUNK][64];
    const int s0 = k * CHUNK;
    const float4* bc4 = (const float4*)(bc + ((size_t)(b * S_LEN + s0)) * 128);
    for (int idx = threadIdx.x; idx < CHUNK * 16; idx += 256) {
        int r = idx >> 4, q = idx & 15;
        *(float4*)&Bs[r][q << 2] = bc4[r * 32 + q];
    }
    __syncthreads();
    const float A = -expf(alog[c]);
    const float wdtc = wdt[c], dtbc = dtb[c];
    float hs[NST];
#pragma unroll
    for (int n = 0; n < NST; ++n) hs[n] = 0.f;
    float dtsum = 0.f;
    const float* xcp = xc + ((size_t)(b * S_LEN + s0)) * DI + c;
    for (int s = 0; s < CHUNK; ++s) {
        float xcv = xcp[(size_t)s * DI];
        float t = fmaf(xcv, wdtc, dtbc);
        float dtv = (t > 20.f) ? t : log1pf(expf(t));
        float decay = expf(dtv * A);
        float coef = dtv * xcv;
        dtsum += dtv;
#pragma unroll
        for (int n4 = 0; n4 < 16; ++n4) {
            float4 bv = *(const float4*)&Bs[s][n4 << 2];
            hs[n4 * 4 + 0] = fmaf(decay, hs[n4 * 4 + 0], coef * bv.x);
            hs[n4 * 4 + 1] = fmaf(decay, hs[n4 * 4 + 1], coef * bv.y);
            hs[n4 * 4 + 2] = fmaf(decay, hs[n4 * 4 + 2], coef * bv.z);
            hs[n4 * 4 + 3] = fmaf(decay, hs[n4 * 4 + 3], coef * bv.w);
        }
    }
    float* hp = hend + (((size_t)(b * NCH + k)) * DI + c) * NST;
#pragma unroll
    for (int n = 0; n < NST; n += 4) {
        float4 v; v.x = hs[n]; v.y = hs[n + 1]; v.z = hs[n + 2]; v.w = hs[n + 3];
        *(float4*)(hp + n) = v;
    }
    pprod[((size_t)(b * NCH + k)) * DI + c] = expf(dtsum * A);
}

/* ------------ scan pass 2 ------------ */
__global__ __launch_bounds__(256) void scan2_k(const float* __restrict__ hend,
                                               const float* __restrict__ pprod,
                                               float* __restrict__ hin) {
    size_t g = (size_t)blockIdx.x * 256 + threadIdx.x;
    int n = (int)(g & 63);
    int c = (int)((g >> 6) & (DI - 1));
    int b = (int)(g >> 17);
    float h = 0.f;
    for (int k = 0; k < NCH; ++k) {
        size_t base = (size_t)(b * NCH + k) * DI + c;
        hin[base * NST + n] = h;
        h = fmaf(pprod[base], h, hend[base * NST + n]);
    }
}

/* ------------ scan pass 3 ------------ */
__global__ __launch_bounds__(256) void scan3_k(float* __restrict__ xcio,
                                               const float* __restrict__ bc,
                                               const float* __restrict__ xz,
                                               const float* __restrict__ alog,
                                               const float* __restrict__ wdt,
                                               const float* __restrict__ dtb,
                                               const float* __restrict__ dskip,
                                               const float* __restrict__ hin) {
    const int b = blockIdx.z, k = blockIdx.y;
    const int c = blockIdx.x * 256 + threadIdx.x;
    __shared__ float Bs[CHUNK][64];
    __shared__ float Cs[CHUNK][64];
    const int s0 = k * CHUNK;
    const float4* bc4 = (const float4*)(bc + ((size_t)(b * S_LEN + s0)) * 128);
    for (int idx = threadIdx.x; idx < CHUNK * 32; idx += 256) {
        int r = idx >> 5, q = idx & 31;
        float4 v = bc4[r * 32 + q];
        if (q < 16) *(float4*)&Bs[r][q << 2] = v;
        else        *(float4*)&Cs[r][(q - 16) << 2] = v;
    }
    __syncthreads();
    const float A = -expf(alog[c]);
    const float wdtc = wdt[c], dtbc = dtb[c], skipc = dskip[c];
    float hs[NST];
    const float* hp = hin + (((size_t)(b * NCH + k)) * DI + c) * NST;
#pragma unroll
    for (int n = 0; n < NST; n += 4) {
        float4 v = *(const float4*)(hp + n);
        hs[n] = v.x; hs[n + 1] = v.y; hs[n + 2] = v.z; hs[n + 3] = v.w;
    }
    float* xcp = xcio + ((size_t)(b * S_LEN + s0)) * DI + c;
    const float* zp = xz + ((size_t)(b * S_LEN + s0)) * 4096 + DI + c;
    for (int s = 0; s < CHUNK; ++s) {
        float xcv = xcp[(size_t)s * DI];
        float t = fmaf(xcv, wdtc, dtbc);
        float dtv = (t > 20.f) ? t : log1pf(expf(t));
        float decay = expf(dtv * A);
        float coef = dtv * xcv;
        float y = 0.f;
#pragma unroll
        for (int n4 = 0; n4 < 16; ++n4) {
            float4 bv = *(const float4*)&Bs[s][n4 << 2];
            float4 cv = *(const float4*)&Cs[s][n4 << 2];
            float h0 = fmaf(decay, hs[n4 * 4 + 0], coef * bv.x);
            float h1 = fmaf(decay, hs[n4 * 4 + 1], coef * bv.y);
            float h2 = fmaf(decay, hs[n4 * 4 + 2], coef * bv.z);
            float h3 = fmaf(decay, hs[n4 * 4 + 3], coef * bv.w);
            hs[n4 * 4 + 0] = h0; hs[n4 * 4 + 1] = h1;
            hs[n4 * 4 + 2] = h2; hs[n4 * 4 + 3] = h3;
            y = fmaf(h0, cv.x, y); y = fmaf(h1, cv.y, y);
            y = fmaf(h2, cv.z, y); y = fmaf(h3, cv.w, y);
        }
        y = fmaf(skipc, xcv, y);
        float z = zp[(size_t)s * 4096];
        float sz = z / (1.f + expf(-z));
        xcp[(size_t)s * DI] = y * sz;
    }
}

/* ------------ wavelet split -> a bf16x3 planes + det fp32 ------------ */
__global__ __launch_bounds__(256) void wsplit_k(const float* __restrict__ ln,
                                                unsigned short* __restrict__ ah,
                                                unsigned short* __restrict__ am,
                                                unsigned short* __restrict__ al,
                                                float* __restrict__ det) {
    size_t f = (size_t)blockIdx.x * 256 + threadIdx.x;
    int d4 = (int)(f & 255);
    size_t l = f >> 8;
    size_t b = l >> 10;
    size_t li = l & 1023;
    const float4* ln4 = (const float4*)ln;
    float4 xe = ln4[(b * S_LEN + 2 * li) * 256 + d4];
    float4 xo = ln4[(b * S_LEN + 2 * li + 1) * 256 + d4];
    float4 av, dv;
    av.x = (xe.x + xo.x) * INVR2; dv.x = (xe.x - xo.x) * INVR2;
    av.y = (xe.y + xo.y) * INVR2; dv.y = (xe.y - xo.y) * INVR2;
    av.z = (xe.z + xo.z) * INVR2; dv.z = (xe.z - xo.z) * INVR2;
    av.w = (xe.w + xo.w) * INVR2; dv.w = (xe.w - xo.w) * INVR2;
    ushort4 h4, m4, l4;
    split3q(av, h4, m4, l4);
    ((ushort4*)ah)[f] = h4;
    ((ushort4*)am)[f] = m4;
    ((ushort4*)al)[f] = l4;
    ((float4*)det)[f] = dv;
}

/* ------------ attention partial: half KV, fused-qkv input (stride 3072),
   R10-proven direct-LDS staging (no reg prefetch), 52 KB, 3 blk/CU ------------ */
__global__ __launch_bounds__(256) void wlam_attn_k(const float* __restrict__ qkv,
                                                   float* __restrict__ o0,
                                                   float* __restrict__ o1,
                                                   float* __restrict__ ml) {
    __shared__ float Qt[64][68];
    __shared__ float KPt[64][68];
    __shared__ float Vs[64][68];
    const int tid = threadIdx.x;
    const int b = blockIdx.z >> 1, half = blockIdx.z & 1;
    const int hh = blockIdx.y;
    const int q0 = blockIdx.x << 6;
    const int tx = tid & 15, ty = tid >> 4;
    const int sr = tid & 63, sc4 = (tid >> 6) << 4;
    {
        const float* qp = qkv + ((size_t)(b * LH + q0 + sr)) * 3072 + hh * HD + sc4;
        float4 v0 = *(const float4*)qp;
        float4 v1 = *(const float4*)(qp + 4);
        float4 v2 = *(const float4*)(qp + 8);
        float4 v3 = *(const float4*)(qp + 12);
        Qt[sc4 + 0][sr] = v0.x;  Qt[sc4 + 1][sr] = v0.y;  Qt[sc4 + 2][sr] = v0.z;  Qt[sc4 + 3][sr] = v0.w;
        Qt[sc4 + 4][sr] = v1.x;  Qt[sc4 + 5][sr] = v1.y;  Qt[sc4 + 6][sr] = v1.z;  Qt[sc4 + 7][sr] = v1.w;
        Qt[sc4 + 8][sr] = v2.x;  Qt[sc4 + 9][sr] = v2.y;  Qt[sc4 + 10][sr] = v2.z; Qt[sc4 + 11][sr] = v2.w;
        Qt[sc4 + 12][sr] = v3.x; Qt[sc4 + 13][sr] = v3.y; Qt[sc4 + 14][sr] = v3.z; Qt[sc4 + 15][sr] = v3.w;
    }
    float mrow[4] = {-INFINITY, -INFINITY, -INFINITY, -INFINITY};
    float lrow[4] = {0.f, 0.f, 0.f, 0.f};
    float oacc[4][4] = {};
    const int c0beg = half << 9;
    for (int c0 = c0beg; c0 < c0beg + 512; c0 += 64) {
        __syncthreads();
        {
            const float* kp = qkv + ((size_t)(b * LH + c0 + sr)) * 3072 + 1024 + hh * HD + sc4;
            float4 v0 = *(const float4*)kp;
            float4 v1 = *(const float4*)(kp + 4);
            float4 v2 = *(const float4*)(kp + 8);
            float4 v3 = *(const float4*)(kp + 12);
            KPt[sc4 + 0][sr] = v0.x;  KPt[sc4 + 1][sr] = v0.y;  KPt[sc4 + 2][sr] = v0.z;  KPt[sc4 + 3][sr] = v0.w;
            KPt[sc4 + 4][sr] = v1.x;  KPt[sc4 + 5][sr] = v1.y;  KPt[sc4 + 6][sr] = v1.z;  KPt[sc4 + 7][sr] = v1.w;
            KPt[sc4 + 8][sr] = v2.x;  KPt[sc4 + 9][sr] = v2.y;  KPt[sc4 + 10][sr] = v2.z; KPt[sc4 + 11][sr] = v2.w;
            KPt[sc4 + 12][sr] = v3.x; KPt[sc4 + 13][sr] = v3.y; KPt[sc4 + 14][sr] = v3.z; KPt[sc4 + 15][sr] = v3.w;
            const float* vp = kp + 1024;
            *(float4*)&Vs[sr][sc4 + 0]  = *(const float4*)vp;
            *(float4*)&Vs[sr][sc4 + 4]  = *(const float4*)(vp + 4);
            *(float4*)&Vs[sr][sc4 + 8]  = *(const float4*)(vp + 8);
            *(float4*)&Vs[sr][sc4 + 12] = *(const float4*)(vp + 12);
        }
        __syncthreads();
        float s[4][4] = {};
#pragma unroll
        for (int d = 0; d < 64; ++d) {
            float4 a4 = *(const float4*)&Qt[d][ty << 2];
            float4 b4 = *(const float4*)&KPt[d][tx << 2];
            float aa[4] = {a4.x, a4.y, a4.z, a4.w};
            float bb[4] = {b4.x, b4.y, b4.z, b4.w};
#pragma unroll
            for (int i = 0; i < 4; ++i)
#pragma unroll
                for (int j = 0; j < 4; ++j)
                    s[i][j] = fmaf(aa[i], bb[j], s[i][j]);
        }
        float rm[4], mn[4], corr[4], rs[4];
#pragma unroll
        for (int i = 0; i < 4; ++i) {
            s[i][0] *= 0.125f; s[i][1] *= 0.125f; s[i][2] *= 0.125f; s[i][3] *= 0.125f;
            rm[i] = fmaxf(fmaxf(s[i][0], s[i][1]), fmaxf(s[i][2], s[i][3]));
        }
#pragma unroll
        for (int off = 8; off; off >>= 1) {
#pragma unroll
            for (int i = 0; i < 4; ++i) rm[i] = fmaxf(rm[i], __shfl_xor(rm[i], off));
        }
#pragma unroll
        for (int i = 0; i < 4; ++i) {
            mn[i] = fmaxf(mrow[i], rm[i]);
            corr[i] = expf(mrow[i] - mn[i]);
            mrow[i] = mn[i];
            s[i][0] = expf(s[i][0] - mn[i]); s[i][1] = expf(s[i][1] - mn[i]);
            s[i][2] = expf(s[i][2] - mn[i]); s[i][3] = expf(s[i][3] - mn[i]);
            rs[i] = (s[i][0] + s[i][1]) + (s[i][2] + s[i][3]);
        }
#pragma unroll
        for (int off = 8; off; off >>= 1) {
#pragma unroll
            for (int i = 0; i < 4; ++i) rs[i] += __shfl_xor(rs[i], off);
        }
#pragma unroll
        for (int i = 0; i < 4; ++i) {
            lrow[i] = lrow[i] * corr[i] + rs[i];
            oacc[i][0] *= corr[i]; oacc[i][1] *= corr[i];
            oacc[i][2] *= corr[i]; oacc[i][3] *= corr[i];
        }
        __syncthreads();   /* all QK reads of KPt done */
#pragma unroll
        for (int j = 0; j < 4; ++j) {
            float4 pv; pv.x = s[0][j]; pv.y = s[1][j]; pv.z = s[2][j]; pv.w = s[3][j];
            *(float4*)&KPt[(tx << 2) + j][ty << 2] = pv;
        }
        __syncthreads();
#pragma unroll
        for (int kk = 0; kk < 64; ++kk) {
            float4 pa = *(const float4*)&KPt[kk][ty << 2];
            float4 vb = *(const float4*)&Vs[kk][tx << 2];
            float aa[4] = {pa.x, pa.y, pa.z, pa.w};
            float bb[4] = {vb.x, vb.y, vb.z, vb.w};
#pragma unroll
            for (int i = 0; i < 4; ++i)
#pragma unroll
                for (int j = 0; j < 4; ++j)
                    oacc[i][j] = fmaf(aa[i], bb[j], oacc[i][j]);
        }
    }
    float* op = half ? o1 : o0;
#pragma unroll
    for (int i = 0; i < 4; ++i) {
        int rrow = q0 + (ty << 2) + i;
        float4 ov;
        ov.x = oacc[i][0]; ov.y = oacc[i][1]; ov.z = oacc[i][2]; ov.w = oacc[i][3];
        *(float4*)(op + ((size_t)(b * LH + rrow)) * DM + hh * HD + (tx << 2)) = ov;
        if (tx == 0) {
            size_t mi = (size_t)half * 65536 + ((size_t)(b * LH + rrow) * NH + hh) * 2;
            ml[mi] = mrow[i];
            ml[mi + 1] = lrow[i];
        }
    }
}

/* ------------ attention merge: exact 2-way softmax merge -> bf16x3 planes ------------ */
__global__ __launch_bounds__(256) void attn_merge_k(const float* __restrict__ o0,
                                                    const float* __restrict__ o1,
                                                    const float* __restrict__ ml,
                                                    unsigned short* __restrict__ ph,
                                                    unsigned short* __restrict__ pm,
                                                    unsigned short* __restrict__ pl) {
    int row = blockIdx.x;
    int t = threadIdx.x;
    int hh = t >> 4;
    size_t idx = ((size_t)row * NH + hh) * 2;
    float m0 = ml[idx], l0 = ml[idx + 1];
    float m1 = ml[65536 + idx], l1 = ml[65536 + idx + 1];
    float m = fmaxf(m0, m1);
    float w0 = expf(m0 - m), w1 = expf(m1 - m);
    float inv = 1.f / (l0 * w0 + l1 * w1);
    float4 a = ((const float4*)(o0 + (size_t)row * DM))[t];
    float4 bv = ((const float4*)(o1 + (size_t)row * DM))[t];
    float4 o;
    o.x = (a.x * w0 + bv.x * w1) * inv;
    o.y = (a.y * w0 + bv.y * w1) * inv;
    o.z = (a.z * w0 + bv.z * w1) * inv;
    o.w = (a.w * w0 + bv.w * w1) * inv;
    ushort4 h4, m4, l4;
    split3q(o, h4, m4, l4);
    size_t f = (size_t)row * 256 + t;
    ((ushort4*)ph)[f] = h4;
    ((ushort4*)pm)[f] = m4;
    ((ushort4*)pl)[f] = l4;
}

/* ------------ MoE gate (fp32): top-2 + softmax ------------ */
__global__ __launch_bounds__(256) void moe_gate_k(const float* __restrict__ X,
                                                  const float* __restrict__ wg,
                                                  int* __restrict__ toke,
                                                  float* __restrict__ tokw) {
    const int wv = threadIdx.x >> 6, lane = threadIdx.x & 63;
    const int t = blockIdx.x * 4 + wv;
    const float* x = X + (size_t)t * DM;
    float acc[8] = {0, 0, 0, 0, 0, 0, 0, 0};
    for (int d = lane; d < DM; d += 64) {
        float xv = x[d];
        const float4* wg4 = (const float4*)(wg + (size_t)d * 8);
        float4 wa = wg4[0], wb = wg4[1];
        acc[0] = fmaf(xv, wa.x, acc[0]); acc[1] = fmaf(xv, wa.y, acc[1]);
        acc[2] = fmaf(xv, wa.z, acc[2]); acc[3] = fmaf(xv, wa.w, acc[3]);
        acc[4] = fmaf(xv, wb.x, acc[4]); acc[5] = fmaf(xv, wb.y, acc[5]);
        acc[6] = fmaf(xv, wb.z, acc[6]); acc[7] = fmaf(xv, wb.w, acc[7]);
    }
#pragma unroll
    for (int off = 32; off; off >>= 1) {
#pragma unroll
        for (int j = 0; j < 8; ++j) acc[j] += __shfl_xor(acc[j], off);
    }
    if (lane == 0) {
        int i0 = 0; float v0 = acc[0];
#pragma unroll
        for (int e2 = 1; e2 < 8; ++e2) if (acc[e2] > v0) { v0 = acc[e2]; i0 = e2; }
        int i1 = -1; float v1 = -INFINITY;
#pragma unroll
        for (int e2 = 0; e2 < 8; ++e2) if (e2 != i0 && acc[e2] > v1) { v1 = acc[e2]; i1 = e2; }
        float r = expf(v1 - v0);
        float den = 1.f + r;
        toke[2 * t] = i0; toke[2 * t + 1] = i1;
        tokw[2 * t] = 1.f / den; tokw[2 * t + 1] = r / den;
    }
}

__global__ __launch_bounds__(256) void moe_count_k(const int* __restrict__ toke, int* __restrict__ counts) {
    int t = blockIdx.x * 256 + threadIdx.x;
    atomicAdd(&counts[toke[2 * t]], 1);
    atomicAdd(&counts[toke[2 * t + 1]], 1);
}

__global__ void moe_tiles_k(const int* __restrict__ counts, int* __restrict__ ntile,
                            int* __restrict__ eoff, int* __restrict__ tileE,
                            int* __restrict__ tileR, int* __restrict__ tileC) {
    if (threadIdx.x == 0 && blockIdx.x == 0) {
        int off = 0, nt = 0;
        for (int e = 0; e < NEXP; ++e) {
            eoff[e] = off;
            int c = counts[e];
            for (int r = 0; r < c; r += 128) {
                tileE[nt] = e;
                tileR[nt] = off + r;
                tileC[nt] = (c - r < 128) ? (c - r) : 128;
                ++nt;
            }
            off += c;
        }
        ntile[0] = nt;
    }
}

__global__ __launch_bounds__(256) void moe_place_k(const int* __restrict__ toke,
                                                   const float* __restrict__ tokw,
                                                   const int* __restrict__ eoff,
                                                   int* __restrict__ cursor,
                                                   int* __restrict__ rtok,
                                                   float* __restrict__ rgate,
                                                   int* __restrict__ rexp,
                                                   int* __restrict__ rowof) {
    int t = blockIdx.x * 256 + threadIdx.x;
#pragma unroll
    for (int kk = 0; kk < 2; ++kk) {
        int e = toke[2 * t + kk];
        float wv = tokw[2 * t + kk];
        int r = eoff[e] + atomicAdd(&cursor[e], 1);
        rtok[r] = t; rgate[r] = wv; rexp[r] = e;
        rowof[2 * t + kk] = r;
    }
}

/* ------------ MoE combine ------------ */
__global__ __launch_bounds__(256) void moe_combine_k(float* __restrict__ h,
                                                     const float* __restrict__ P,
                                                     const int* __restrict__ rowof,
                                                     const float* __restrict__ rgate,
                                                     const float* __restrict__ masks) {
    int t = blockIdx.x;
    int r0 = rowof[2 * t], r1 = rowof[2 * t + 1];
    float g0 = rgate[r0], g1 = rgate[r1];
    float m = masks[(t >> 11) * 4 + 3];
    float4 a = ((const float4*)(P + (size_t)r0 * DM))[threadIdx.x];
    float4 bq = ((const float4*)(P + (size_t)r1 * DM))[threadIdx.x];
    float4* h4 = (float4*)(h + (size_t)t * DM);
    float4 hv = h4[threadIdx.x];
    hv.x += m * (g0 * a.x + g1 * bq.x);
    hv.y += m * (g0 * a.y + g1 * bq.y);
    hv.z += m * (g0 * a.z + g1 * bq.z);
    hv.w += m * (g0 * a.w + g1 * bq.w);
    h4[threadIdx.x] = hv;
}

extern "C" void kernel_launch(void* const* d_in, const int* in_sizes, int n_in,
                              void* d_out, int out_size, void* d_ws, size_t ws_size,
                              hipStream_t stream) {
    const float* hidden    = (const float*)d_in[0];
    const float* router_w  = (const float*)d_in[1];
    const float* router_b  = (const float*)d_in[2];
    const float* ln_g      = (const float*)d_in[3];
    const float* ln_b      = (const float*)d_in[4];
    const float* m_win     = (const float*)d_in[5];
    const float* m_conv    = (const float*)d_in[6];
    const float* m_alog    = (const float*)d_in[7];
    const float* m_wbc     = (const float*)d_in[8];
    const float* m_wdt     = (const float*)d_in[9];
    const float* m_dtb     = (const float*)d_in[10];
    const float* m_dskip   = (const float*)d_in[11];
    const float* m_wout    = (const float*)d_in[12];
    const float* tc_theta  = (const float*)d_in[13];
    const float* tc_w      = (const float*)d_in[14];
    const float* tc_b      = (const float*)d_in[15];
    const float* w_q       = (const float*)d_in[16];
    const float* w_k       = (const float*)d_in[17];
    const float* w_v       = (const float*)d_in[18];
    const float* w_o       = (const float*)d_in[19];
    const float* wlam_cv   = (const float*)d_in[20];
    const float* moe_wg    = (const float*)d_in[21];
    const float* moe_w1    = (const float*)d_in[22];
    const float* moe_b1    = (const float*)d_in[23];
    const float* moe_w2    = (const float*)d_in[24];
    const float* moe_b2    = (const float*)d_in[25];
    float* h = (float*)d_out;
    float* w = (float*)d_ws;
    unsigned short* BIGH = (unsigned short*)(w + OFF_BIG);
    unsigned short* XCU  = (unsigned short*)(w + OFF_XC);
    unsigned short* OUTU = (unsigned short*)(w + OFF_OUT);
#define UPB(F) (BIGH + 2 * (size_t)(F))
#define UPX(F) (XCU  + 2 * (size_t)(F))
#define UPO(F) (OUTU + 2 * (size_t)(F))

    hipMemsetAsync(d_ws, 0, 2064 * sizeof(float), stream);

    pooled_k<<<dim3(4, 2, 16), 256, 0, stream>>>(hidden, w + OFF_POOLED);
    router_k<<<1, 256, 0, stream>>>(w + OFF_POOLED, router_w, router_b, w + OFF_MASKS);

    /* ---- mamba ---- */
    ln0_copy_k<<<TT, 256, 0, stream>>>(hidden, ln_g + 0 * DM, ln_b + 0 * DM, h,
                                       UPX(0), UPX(2097152), UPX(4194304));
    transb3_k<<<dim3(16, 64), 256, 0, stream>>>(m_win, UPO(0), UPO(2097152), UPX(6291456), 4096, 1024);
    mmx3_k<<<dim3(32, 32), 256, 0, stream>>>(UPX(0), UPX(2097152), UPX(4194304),
                                             UPO(0), UPO(2097152), UPX(6291456),
                                             w + OFF_BIG, 1024, 1024, 4096, 1024);
    mamba_conv_k<<<8192, 256, 0, stream>>>(w + OFF_BIG, m_conv, w + OFF_XC);
    gemmsk_f32<<<dim3(64, 2, 8), 256, 0, stream>>>(w + OFF_XC, DI, m_wbc, 128, w + OFF_LN, 128, 256);
    wbc_red_k<<<2048, 256, 0, stream>>>(w + OFF_LN, w + OFF_BC);
    scan1_k<<<dim3(8, NCH, B_SZ), 256, 0, stream>>>(w + OFF_XC, w + OFF_BC,
                                                    m_alog, m_wdt, m_dtb,
                                                    w + OFF_LN, w + OFF_PPROD);
    scan2_k<<<1024, 256, 0, stream>>>(w + OFF_LN, w + OFF_PPROD, w + OFF_OUT);
    scan3_k<<<dim3(8, NCH, B_SZ), 256, 0, stream>>>(w + OFF_XC, w + OFF_BC, w + OFF_BIG,
                                                    m_alog, m_wdt, m_dtb, m_dskip,
                                                    w + OFF_OUT);
    split3_k<<<8192, 256, 0, stream>>>(w + OFF_XC, UPB(0), UPB(4194304), UPB(8388608));
    transb3_k<<<dim3(32, 16), 256, 0, stream>>>(m_wout, UPB(12582912), UPB(13631488), UPB(14680064), 1024, 2048);
    mmx3_k<<<dim3(32, 8), 256, 0, stream>>>(UPB(0), UPB(4194304), UPB(8388608),
                                            UPB(12582912), UPB(13631488), UPB(14680064),
                                            w + OFF_OUT, 2048, 2048, 1024, 2048);
    add_ln_k<<<TT, 256, 0, stream>>>(h, w + OFF_OUT, w + OFF_MASKS, 0,
                                     ln_g + 1 * DM, ln_b + 1 * DM, w + OFF_LN,
                                     UPB(0), UPB(2097152), UPB(4194304));

    /* ---- timecrystal ---- */
    transb3_k<<<dim3(16, 16), 256, 0, stream>>>(tc_w, UPB(6291456), UPB(6815744), UPB(7340032), 1024, 1024);
    mmx3_k<<<dim3(32, 8), 256, 0, stream>>>(UPB(0), UPB(2097152), UPB(4194304),
                                            UPB(6291456), UPB(6815744), UPB(7340032),
                                            w + OFF_OUT, 1024, 1024, 1024, 1024);
    tc_ln_k<<<TT, 256, 0, stream>>>(h, w + OFF_LN, w + OFF_OUT, tc_b, tc_theta, w + OFF_MASKS,
                                    ln_g + 2 * DM, ln_b + 2 * DM, w + OFF_LN);

    /* ---- wavelet attention ---- */
    float* wdet = w + OFF_BIG;                 /* det f32 [2048][1024] at BIG 0..2M */
    wsplit_k<<<2048, 256, 0, stream>>>(w + OFF_LN, UPB(4194304), UPB(5242880), UPB(6291456), wdet);
    /* fused QKV weight planes (one launch): q/k/v at +z*1048576 elems within each plane group */
    transb3m_k<<<dim3(16, 16, 3), 256, 0, stream>>>(w_q, w_k, w_v,
                                                    UPB(7340032), UPB(8912896), UPB(10485760));
    transb3_k<<<dim3(16, 16), 256, 0, stream>>>(w_o, UPB(12058624), UPB(12582912), UPB(13107200), 1024, 1024);
    float* wqkv = w + OFF_XC;                  /* [2048][3072] f32 */
    float* wo0  = w + OFF_XC + 6291456;        /* partial half 0 */
    float* wo1  = w + OFF_OUT;                 /* partial half 1 */
    float* wml  = w + OFF_OUT + 2097152;       /* (m,l) 2x65536 */
    mmx3_k<<<dim3(16, 24), 256, 0, stream>>>(UPB(4194304), UPB(5242880), UPB(6291456),
                                             UPB(7340032), UPB(8912896), UPB(10485760),
                                             wqkv, 1024, 1024, 3072, 1024);
    wlam_attn_k<<<dim3(16, NH, B_SZ * 2), 256, 0, stream>>>(wqkv, wo0, wo1, wml);
    attn_merge_k<<<2048, 256, 0, stream>>>(wo0, wo1, wml,
                                           UPB(13631488), UPB(14680064), UPB(15728640));
    mmx3_k<<<dim3(16, 8), 256, 0, stream>>>(UPB(13631488), UPB(14680064), UPB(15728640),
                                            UPB(12058624), UPB(12582912), UPB(13107200),
                                            w + OFF_OUT, 1024, 1024, 1024, 1024);
    wpost_ln_k<<<TT, 256, 0, stream>>>(h, w + OFF_OUT, wdet, wlam_cv, w + OFF_MASKS,
                                       ln_g + 3 * DM, ln_b + 3 * DM, w + OFF_LN,
                                       UPB(MB_LNB));

    /* ---- MoE: fp32 gate + bf16 MFMA experts ---- */
    moe_gate_k<<<1024, 256, 0, stream>>>(w + OFF_LN, moe_wg, (int*)(w + OFF_TOKE), w + OFF_TOKW);
    moe_count_k<<<16, 256, 0, stream>>>((const int*)(w + OFF_TOKE), (int*)(w + OFF_COUNTS));
    moe_tiles_k<<<1, 64, 0, stream>>>((const int*)(w + OFF_COUNTS), (int*)(w + OFF_NTILE),
                                      (int*)(w + OFF_EOFF), (int*)(w + OFF_TILEE),
                                      (int*)(w + OFF_TILER), (int*)(w + OFF_TILEC));
    moe_place_k<<<16, 256, 0, stream>>>((const int*)(w + OFF_TOKE), w + OFF_TOKW,
                                        (const int*)(w + OFF_EOFF), (int*)(w + OFF_CURSOR),
                                        (int*)(w + OFF_RTOK), w + OFF_RGATE,
                                        (int*)(w + OFF_REXP), (int*)(w + OFF_ROWOF));
    for (int ci = 0; ci < 4; ++ci) {
        transb2_k<<<dim3(16, 16, 16), 256, 0, stream>>>(moe_w1 + (size_t)ci * CHK,
                                                        moe_w2 + (size_t)ci * CHK * DM,
                                                        UPB(MB_W1T), UPB(MB_W2T));
        mm_k<2><<<dim3(MAXTILE, 8), 256, 0, stream>>>(UPB(MB_LNB), UPB(MB_W1T), UPB(MB_HB),
                                                      1024, 1024, 1024, 1024,
                                                      moe_b1, ci * CHK,
                                                      (const int*)(w + OFF_NTILE), (const int*)(w + OFF_TILEE),
                                                      (const int*)(w + OFF_TILER), (const int*)(w + OFF_TILEC),
                                                      (const int*)(w + OFF_RTOK));
        if (ci == 0) {
            mm_k<4><<<dim3(MAXTILE, 8), 256, 0, stream>>>(UPB(MB_HB), UPB(MB_W2T),
                                                          w + OFF_XC, 1024, 1024, 1024, 1024,
                                                          moe_b2, 0,
                                                          (const int*)(w + OFF_NTILE), (const int*)(w + OFF_TILEE),
                                                          (const int*)(w + OFF_TILER), (const int*)(w + OFF_TILEC),
                                                          nullptr);
        } else {
            mm_k<3><<<dim3(MAXTILE, 8), 256, 0, stream>>>(UPB(MB_HB), UPB(MB_W2T),
                                                          w + OFF_XC, 1024, 1024, 1024, 1024,
                                                          nullptr, 0,
                                                          (const int*)(w + OFF_NTILE), (const int*)(w + OFF_TILEE),
                                                          (const int*)(w + OFF_TILER), (const int*)(w + OFF_TILEC),
                                                          nullptr);
        }
    }
    moe_combine_k<<<4096, 256, 0, stream>>>(h, w + OFF_XC, (const int*)(w + OFF_ROWOF),
                                            w + OFF_RGATE, w + OFF_MASKS);
#undef UPB
#undef UPX
#undef UPO
}